// Round 4
// baseline (8698.188 us; speedup 1.0000x reference)
//
#include <hip/hip_runtime.h>

#define NN 50000
#define NE 400000
#define NT 300000
#define NQ 200000
#define DM 256
#define FIN 128
#define NRBF 40
#define BETA_RBF 40.0f
#define TOTALP 397569

typedef unsigned int u32;
typedef unsigned short u16;

// ---- bf16 helpers ----
static __device__ __forceinline__ float bf2f(u16 h) {
  return __uint_as_float(((u32)h) << 16);
}
static __device__ __forceinline__ u16 f2bf(float f) {
  u32 u = __float_as_uint(f);
  u32 r = (u + 0x7FFFu + ((u >> 16) & 1u)) >> 16;  // RNE
  return (u16)r;
}
static __device__ __forceinline__ float4 ld4bf(const u16* p) {
  ushort4 v = *reinterpret_cast<const ushort4*>(p);
  return float4{bf2f(v.x), bf2f(v.y), bf2f(v.z), bf2f(v.w)};
}
static __device__ __forceinline__ float4 ld4f(const float* p) {
  return *reinterpret_cast<const float4*>(p);
}
// dtype-flag scalar load (isf32: 1 = fp32 buffer, 0 = bf16 buffer)
static __device__ __forceinline__ float ldsc(const void* p, int isf, size_t i) {
  return isf ? ((const float*)p)[i] : bf2f(((const u16*)p)[i]);
}
static __device__ __forceinline__ float lk(float t) { return t >= 0.f ? t : 0.2f * t; }
static __device__ __forceinline__ u32 f2o(float f) {
  u32 u = __float_as_uint(f);
  return (u & 0x80000000u) ? ~u : (u | 0x80000000u);
}
static __device__ __forceinline__ float o2f(u32 e) {
  u32 b = (e & 0x80000000u) ? (e & 0x7fffffffu) : ~e;
  return __uint_as_float(b);
}

struct F3 { float x, y, z; };
static __device__ __forceinline__ F3 ldpos(const void* pos, int isf, int i) {
  F3 r; r.x = ldsc(pos, isf, 3 * i); r.y = ldsc(pos, isf, 3 * i + 1); r.z = ldsc(pos, isf, 3 * i + 2);
  return r;
}
static __device__ __forceinline__ F3 sub3(F3 a, F3 b) { return F3{a.x - b.x, a.y - b.y, a.z - b.z}; }
static __device__ __forceinline__ float dot3(F3 a, F3 b) { return a.x * b.x + a.y * b.y + a.z * b.z; }
static __device__ __forceinline__ F3 cross3(F3 a, F3 b) {
  return F3{a.y * b.z - a.z * b.y, a.z * b.x - a.x * b.z, a.x * b.y - a.y * b.x};
}
static __device__ __forceinline__ float norm3(F3 v) { return sqrtf(dot3(v, v) + 1e-12f); }
static __device__ __forceinline__ float angle_at(F3 a, F3 m, F3 b) {
  F3 u = sub3(a, m), v = sub3(b, m);
  float c = dot3(u, v) / (norm3(u) * norm3(v) + 1e-12f);
  c = fminf(fmaxf(c, -1.f + 1e-7f), 1.f - 1e-7f);
  return acosf(c);
}
static __device__ __forceinline__ float dihedral_f(F3 p0, F3 p1, F3 p2, F3 p3) {
  F3 b1 = sub3(p1, p0), b2 = sub3(p2, p1), b3 = sub3(p3, p2);
  F3 n1 = cross3(b1, b2), n2 = cross3(b2, b3);
  float nb2 = norm3(b2) + 1e-12f;
  F3 b2n{b2.x / nb2, b2.y / nb2, b2.z / nb2};
  F3 m1 = cross3(n1, b2n);
  return atan2f(dot3(m1, n2), dot3(n1, n2) + 1e-12f);
}

// param staging table: 30 tensors, cumulative offsets
__device__ const int g_off[31] = {
  0, 32768, 65536, 98304, 131072, 131584, 131840, 142080, 142336, 152576,
  152832, 163072, 163328, 163840, 164096, 165632, 165888, 231424, 231680,
  297216, 297472, 363008, 363264, 363520, 363776, 364032, 396800, 397056,
  397312, 397568, 397569};
struct PtrTab { const void* p[30]; };

// ---- init: gmax=-inf; detect input float dtype via ln_gamma (all ones);
//      classify edge_attr encoding: 0=int32,1=byte,2=float32,3=bf16 ----
__global__ __launch_bounds__(256) void init_detect(const u32* __restrict__ aw,
                                                   const u32* __restrict__ lng,
                                                   u32* __restrict__ gmax,
                                                   int* __restrict__ flags) {
  __shared__ int s_int, s_f32, s_bf;
  if (threadIdx.x == 0) { s_int = 1; s_f32 = 1; s_bf = 1; }
  __syncthreads();
  int li = 1, lf = 1, lb = 1;
  for (int i = threadIdx.x; i < 1024; i += 256) {
    u32 w = aw[i];
    if (w > 1u) li = 0;
    if (w != 0u && w != 0x3F800000u) lf = 0;
    u32 h0 = w & 0xFFFFu, h1 = w >> 16;
    if ((h0 != 0u && h0 != 0x3F80u) || (h1 != 0u && h1 != 0x3F80u)) lb = 0;
  }
  if (!li) atomicAnd(&s_int, 0);
  if (!lf) atomicAnd(&s_f32, 0);
  if (!lb) atomicAnd(&s_bf, 0);
  __syncthreads();
  if (threadIdx.x == 0) {
    flags[0] = s_int ? 0 : (s_f32 ? 2 : (s_bf ? 3 : 1));
    // ln_gamma == 1.0 everywhere: fp32 word = 0x3F800000 (low half 0),
    // bf16 pair = 0x3F803F80 (low half 0x3F80)
    flags[1] = ((lng[0] & 0xFFFFu) == 0x3F80u) ? 0 : 1;  // 1 = fp32 inputs
    gmax[0] = f2o(-INFINITY);
    gmax[1] = f2o(-INFINITY);
    gmax[2] = f2o(-INFINITY);
  }
}

// ---- stage all small params to canonical fp32 ----
__global__ __launch_bounds__(256) void convert_params(PtrTab tab,
                                                      const int* __restrict__ flags,
                                                      float* __restrict__ dst) {
  const int isf = flags[1];
  for (int i = blockIdx.x * blockDim.x + threadIdx.x; i < TOTALP;
       i += gridDim.x * blockDim.x) {
    int t = 0;
    while (i >= g_off[t + 1]) ++t;
    dst[i] = ldsc(tab.p[t], isf, i - g_off[t]);
  }
}

static __device__ __forceinline__ int read_eattr(const void* p, int flag, int e) {
  if (flag == 1) return ((const unsigned char*)p)[e];
  if (flag == 2) return (((const float*)p)[e] != 0.f);
  if (flag == 3) return (((const u16*)p)[e] != 0);
  return ((const int*)p)[e];
}

// ---- node projections: out_bf16 = x @ W + pe[perow] ----
__global__ __launch_bounds__(256) void proj_kernel(const void* __restrict__ x,
                                                   const int* __restrict__ flags,
                                                   const float* __restrict__ W,
                                                   u16* __restrict__ outp, int perow) {
  const int c = threadIdx.x;
  const int n0 = blockIdx.x * 16;
  const int isf = flags[1];
  float dv = expf(-logf(10000.f) * (float)(c & ~1) / 256.f);
  float angv = (float)perow * dv;
  float pe = (c & 1) ? cosf(angv) : sinf(angv);
  float acc[16];
#pragma unroll
  for (int r = 0; r < 16; ++r) acc[r] = pe;
  for (int k = 0; k < FIN; ++k) {
    float wv = W[k * DM + c];
#pragma unroll
    for (int r = 0; r < 16; ++r)
      acc[r] = fmaf(ldsc(x, isf, (size_t)(n0 + r) * FIN + k), wv, acc[r]);
  }
#pragma unroll
  for (int r = 0; r < 16; ++r) outp[(size_t)(n0 + r) * DM + c] = f2bf(acc[r]);
}

// ---- hop1 pass1: one wave per edge, lane = 4 channels ----
__global__ __launch_bounds__(256) void pass1_hop1(
    const void* __restrict__ pos, const int* __restrict__ eidx,
    const void* __restrict__ eattr, const int* __restrict__ flags,
    const u16* __restrict__ p_mid1, const u16* __restrict__ p_dst,
    const float* __restrict__ Wb, const float* __restrict__ bb,
    const float* __restrict__ Wu, const float* __restrict__ bu,
    const float* __restrict__ attn,
    float* __restrict__ score, u32* __restrict__ gmax) {
  const int lane = threadIdx.x & 63;
  const int gw = (blockIdx.x * blockDim.x + threadIdx.x) >> 6;
  const int nw = (gridDim.x * blockDim.x) >> 6;
  const int c4 = lane * 4;
  const int flag = flags[0], isf = flags[1];
  float4 av = ld4f(attn + c4);
  float4 bbv = ld4f(bb + c4), buv = ld4f(bu + c4);
  float4 bsum{bbv.x + buv.x, bbv.y + buv.y, bbv.z + buv.z, bbv.w + buv.w};
  float4 wb0 = ld4f(Wb + c4), wb1 = ld4f(Wb + DM + c4);
  float rmax = -INFINITY;
  for (int e = gw; e < NE; e += nw) {
    int es = eidx[e], ed = eidx[NE + e];
    F3 Ps = ldpos(pos, isf, es), Pd = ldpos(pos, isf, ed);
    float d1 = norm3(sub3(Ps, Pd));
    int ea = read_eattr(eattr, flag, e);
    float4 dm = bsum;
    if (ea) {
      float d1c = fminf(fmaxf(d1, 0.05f), 10.f);
      float t = d1c - 0.25f * (float)lane;
      float my = (lane < NRBF) ? expf(-BETA_RBF * t * t) : 0.f;
#pragma unroll
      for (int r = 0; r < NRBF; ++r) {
        float s = __shfl(my, r, 64);
        float4 wv = ld4f(Wu + r * DM + c4);
        dm.x = fmaf(s, wv.x, dm.x); dm.y = fmaf(s, wv.y, dm.y);
        dm.z = fmaf(s, wv.z, dm.z); dm.w = fmaf(s, wv.w, dm.w);
      }
    } else {
      float d1s = d1 * d1;
      dm.x = fmaf(d1, wb0.x, fmaf(d1s, wb1.x, dm.x));
      dm.y = fmaf(d1, wb0.y, fmaf(d1s, wb1.y, dm.y));
      dm.z = fmaf(d1, wb0.z, fmaf(d1s, wb1.z, dm.z));
      dm.w = fmaf(d1, wb0.w, fmaf(d1s, wb1.w, dm.w));
    }
    float4 m = ld4bf(p_mid1 + (size_t)es * DM + c4);
    float4 dd = ld4bf(p_dst + (size_t)ed * DM + c4);
    float a0 = lk((m.x + dd.x) * dm.x);
    float a1 = lk((m.y + dd.y) * dm.y);
    float a2 = lk((m.z + dd.z) * dm.z);
    float a3 = lk((m.w + dd.w) * dm.w);
    float part = av.x * a0 + av.y * a1 + av.z * a2 + av.w * a3;
    part += __shfl_xor(part, 1, 64);
    part += __shfl_xor(part, 2, 64);
    part += __shfl_xor(part, 4, 64);
    if ((lane & 7) == 0) score[(size_t)e * 8 + (lane >> 3)] = part;
    rmax = fmaxf(rmax, part);
  }
  for (int m = 32; m; m >>= 1) rmax = fmaxf(rmax, __shfl_xor(rmax, m, 64));
  if (lane == 0) atomicMax(gmax, f2o(rmax));
}

// ---- hop2 pass1 ----
__global__ __launch_bounds__(256) void pass1_hop2(
    const void* __restrict__ pos, const int* __restrict__ tdx,
    const int* __restrict__ flags,
    const u16* __restrict__ p_mid2, const u16* __restrict__ p_mid1,
    const u16* __restrict__ p_dst,
    const float* __restrict__ Wu1, const float* __restrict__ bu1,
    const float* __restrict__ Wang, const float* __restrict__ bang,
    const float* __restrict__ attn,
    float* __restrict__ score, u32* __restrict__ gmax) {
  const int lane = threadIdx.x & 63;
  const int gw = (blockIdx.x * blockDim.x + threadIdx.x) >> 6;
  const int nw = (gridDim.x * blockDim.x) >> 6;
  const int c4 = lane * 4;
  const int isf = flags[1];
  float4 av = ld4f(attn + c4);
  float4 b1v = ld4f(bu1 + c4), b2v = ld4f(bang + c4);
  float4 bsum{b1v.x + b2v.x, b1v.y + b2v.y, b1v.z + b2v.z, b1v.w + b2v.w};
  float4 wa0 = ld4f(Wang + c4), wa1 = ld4f(Wang + DM + c4);
  float rmax = -INFINITY;
  for (int t = gw; t < NT; t += nw) {
    int ts = tdx[t], tm = tdx[NT + t], td = tdx[2 * NT + t];
    F3 Ps = ldpos(pos, isf, ts), Pm = ldpos(pos, isf, tm), Pd = ldpos(pos, isf, td);
    float d2 = fminf(fmaxf(norm3(sub3(Ps, Pd)), 0.05f), 10.f);
    float ang = angle_at(Ps, Pm, Pd);
    float angs = ang * ang;
    float4 dm;
    dm.x = fmaf(ang, wa0.x, fmaf(angs, wa1.x, bsum.x));
    dm.y = fmaf(ang, wa0.y, fmaf(angs, wa1.y, bsum.y));
    dm.z = fmaf(ang, wa0.z, fmaf(angs, wa1.z, bsum.z));
    dm.w = fmaf(ang, wa0.w, fmaf(angs, wa1.w, bsum.w));
    float t0 = d2 - 0.25f * (float)lane;
    float my = (lane < NRBF) ? expf(-BETA_RBF * t0 * t0) : 0.f;
#pragma unroll
    for (int r = 0; r < NRBF; ++r) {
      float s = __shfl(my, r, 64);
      float4 wv = ld4f(Wu1 + r * DM + c4);
      dm.x = fmaf(s, wv.x, dm.x); dm.y = fmaf(s, wv.y, dm.y);
      dm.z = fmaf(s, wv.z, dm.z); dm.w = fmaf(s, wv.w, dm.w);
    }
    float4 v0 = ld4bf(p_mid2 + (size_t)ts * DM + c4);
    float4 v1 = ld4bf(p_dst + (size_t)td * DM + c4);
    float4 v2 = ld4bf(p_mid1 + (size_t)tm * DM + c4);
    float a0 = lk((v0.x + v1.x + v2.x) * dm.x);
    float a1 = lk((v0.y + v1.y + v2.y) * dm.y);
    float a2 = lk((v0.z + v1.z + v2.z) * dm.z);
    float a3 = lk((v0.w + v1.w + v2.w) * dm.w);
    float part = av.x * a0 + av.y * a1 + av.z * a2 + av.w * a3;
    part += __shfl_xor(part, 1, 64);
    part += __shfl_xor(part, 2, 64);
    part += __shfl_xor(part, 4, 64);
    if ((lane & 7) == 0) score[(size_t)t * 8 + (lane >> 3)] = part;
    rmax = fmaxf(rmax, part);
  }
  for (int m = 32; m; m >>= 1) rmax = fmaxf(rmax, __shfl_xor(rmax, m, 64));
  if (lane == 0) atomicMax(gmax, f2o(rmax));
}

// ---- hop3 pass1 ----
__global__ __launch_bounds__(256) void pass1_hop3(
    const void* __restrict__ pos, const int* __restrict__ qdx,
    const int* __restrict__ flags,
    const u16* __restrict__ p_src, const u16* __restrict__ p_mid2,
    const u16* __restrict__ p_mid1, const u16* __restrict__ p_dst,
    const float* __restrict__ Wu2, const float* __restrict__ bu2,
    const float* __restrict__ Wd, const float* __restrict__ bd,
    const float* __restrict__ attn,
    float* __restrict__ score, u32* __restrict__ gmax) {
  const int lane = threadIdx.x & 63;
  const int gw = (blockIdx.x * blockDim.x + threadIdx.x) >> 6;
  const int nw = (gridDim.x * blockDim.x) >> 6;
  const int c4 = lane * 4;
  const int isf = flags[1];
  float4 av = ld4f(attn + c4);
  float4 b1v = ld4f(bu2 + c4), b2v = ld4f(bd + c4);
  float4 bsum{b1v.x + b2v.x, b1v.y + b2v.y, b1v.z + b2v.z, b1v.w + b2v.w};
  float4 wd0 = ld4f(Wd + c4), wd1 = ld4f(Wd + DM + c4), wd2 = ld4f(Wd + 2 * DM + c4);
  float4 wd3 = ld4f(Wd + 3 * DM + c4), wd4 = ld4f(Wd + 4 * DM + c4), wd5 = ld4f(Wd + 5 * DM + c4);
  float rmax = -INFINITY;
  for (int q = gw; q < NQ; q += nw) {
    int qs = qdx[q], q2 = qdx[NQ + q], q1 = qdx[2 * NQ + q], qd = qdx[3 * NQ + q];
    F3 P0 = ldpos(pos, isf, qs), P1 = ldpos(pos, isf, q2);
    F3 P2 = ldpos(pos, isf, q1), P3 = ldpos(pos, isf, qd);
    float d3 = fminf(fmaxf(norm3(sub3(P0, P3)), 0.05f), 10.f);
    float a1f = angle_at(P0, P1, P2);
    float a2f = angle_at(P1, P2, P3);
    float dh = dihedral_f(P0, P1, P2, P3);
    float f0 = a1f, f1 = a1f * a1f, f2 = a2f, f3 = a2f * a2f, f4 = dh, f5 = dh * dh;
    float4 dm;
    dm.x = bsum.x + f0 * wd0.x + f1 * wd1.x + f2 * wd2.x + f3 * wd3.x + f4 * wd4.x + f5 * wd5.x;
    dm.y = bsum.y + f0 * wd0.y + f1 * wd1.y + f2 * wd2.y + f3 * wd3.y + f4 * wd4.y + f5 * wd5.y;
    dm.z = bsum.z + f0 * wd0.z + f1 * wd1.z + f2 * wd2.z + f3 * wd3.z + f4 * wd4.z + f5 * wd5.z;
    dm.w = bsum.w + f0 * wd0.w + f1 * wd1.w + f2 * wd2.w + f3 * wd3.w + f4 * wd4.w + f5 * wd5.w;
    float t0 = d3 - 0.25f * (float)lane;
    float my = (lane < NRBF) ? expf(-BETA_RBF * t0 * t0) : 0.f;
#pragma unroll
    for (int r = 0; r < NRBF; ++r) {
      float s = __shfl(my, r, 64);
      float4 wv = ld4f(Wu2 + r * DM + c4);
      dm.x = fmaf(s, wv.x, dm.x); dm.y = fmaf(s, wv.y, dm.y);
      dm.z = fmaf(s, wv.z, dm.z); dm.w = fmaf(s, wv.w, dm.w);
    }
    float4 v0 = ld4bf(p_src + (size_t)qs * DM + c4);
    float4 v1 = ld4bf(p_mid2 + (size_t)q2 * DM + c4);
    float4 v2 = ld4bf(p_mid1 + (size_t)q1 * DM + c4);
    float4 v3 = ld4bf(p_dst + (size_t)qd * DM + c4);
    float a0 = lk((v0.x + v1.x + v2.x + v3.x) * dm.x);
    float a1 = lk((v0.y + v1.y + v2.y + v3.y) * dm.y);
    float a2 = lk((v0.z + v1.z + v2.z + v3.z) * dm.z);
    float a3 = lk((v0.w + v1.w + v2.w + v3.w) * dm.w);
    float part = av.x * a0 + av.y * a1 + av.z * a2 + av.w * a3;
    part += __shfl_xor(part, 1, 64);
    part += __shfl_xor(part, 2, 64);
    part += __shfl_xor(part, 4, 64);
    if ((lane & 7) == 0) score[(size_t)q * 8 + (lane >> 3)] = part;
    rmax = fmaxf(rmax, part);
  }
  for (int m = 32; m; m >>= 1) rmax = fmaxf(rmax, __shfl_xor(rmax, m, 64));
  if (lane == 0) atomicMax(gmax, f2o(rmax));
}

// ---- pass2: e = exp(score - gmax), den[dst,h] += e (in-place on score) ----
__global__ __launch_bounds__(256) void pass2_expden(float* __restrict__ score,
                                                    const int* __restrict__ dsti,
                                                    const u32* __restrict__ gmax,
                                                    float* __restrict__ den, int M) {
  int idx = blockIdx.x * blockDim.x + threadIdx.x;
  if (idx >= M * 8) return;
  int e = idx >> 3, h = idx & 7;
  float g = o2f(*gmax);
  float ev = expf(score[idx] - g);
  score[idx] = ev;
  atomicAdd(&den[(size_t)dsti[e] * 8 + h], ev);
}

// ---- pass3: out_n[dst] += srcvec[src] * e/(den+1e-16), wave per edge ----
__global__ __launch_bounds__(256) void pass3_scatter(const u16* __restrict__ srcvec,
                                                     const int* __restrict__ gidx,
                                                     const int* __restrict__ didx,
                                                     const float* __restrict__ score,
                                                     const float* __restrict__ den,
                                                     float* __restrict__ outn, int M) {
  const int lane = threadIdx.x & 63;
  const int gw = (blockIdx.x * blockDim.x + threadIdx.x) >> 6;
  const int nw = (gridDim.x * blockDim.x) >> 6;
  const int h = lane >> 3;
  const int c4 = lane * 4;
  for (int e = gw; e < M; e += nw) {
    int s = gidx[e], d = didx[e];
    float w = score[(size_t)e * 8 + h] / (den[(size_t)d * 8 + h] + 1e-16f);
    float4 v = ld4bf(srcvec + (size_t)s * DM + c4);
    float* op = outn + (size_t)d * DM + c4;
    atomicAdd(op + 0, v.x * w);
    atomicAdd(op + 1, v.y * w);
    atomicAdd(op + 2, v.z * w);
    atomicAdd(op + 3, v.w * w);
  }
}

// ---- output GEMM into fp32 d_out accumulator ----
__global__ __launch_bounds__(256) void gemm_rowpanel(
    const float* __restrict__ A, const float* __restrict__ W, int K,
    float* __restrict__ outp, int accumulate,
    const void* __restrict__ X2, const float* __restrict__ W2, int K2,
    const int* __restrict__ flags,
    const float* __restrict__ b0, const float* __restrict__ b1,
    const float* __restrict__ b2, const float* __restrict__ b3) {
  const int c = threadIdx.x;
  const int n0 = blockIdx.x * 16;
  float acc[16];
  if (accumulate) {
#pragma unroll
    for (int r = 0; r < 16; ++r) acc[r] = outp[(size_t)(n0 + r) * DM + c];
  } else {
    float base = b0[c] + b1[c] + b2[c] + b3[c];
#pragma unroll
    for (int r = 0; r < 16; ++r) acc[r] = base;
  }
  for (int k = 0; k < K; ++k) {
    float wv = W[k * DM + c];
#pragma unroll
    for (int r = 0; r < 16; ++r) acc[r] = fmaf(A[(size_t)(n0 + r) * K + k], wv, acc[r]);
  }
  if (X2) {
    const int isf = flags[1];
    for (int k = 0; k < K2; ++k) {
      float wv = W2[k * DM + c];
#pragma unroll
      for (int r = 0; r < 16; ++r)
        acc[r] = fmaf(ldsc(X2, isf, (size_t)(n0 + r) * K2 + k), wv, acc[r]);
    }
  }
#pragma unroll
  for (int r = 0; r < 16; ++r) outp[(size_t)(n0 + r) * DM + c] = acc[r];
}

// ---- LayerNorm + PReLU, in place on fp32 d_out ----
__global__ __launch_bounds__(256) void ln_prelu(float* __restrict__ outp,
                                                const float* __restrict__ gamma,
                                                const float* __restrict__ beta,
                                                const float* __restrict__ pw) {
  __shared__ float red[8];
  const int c = threadIdx.x, w = c >> 6, l = c & 63;
  float pwv = pw[0];
  float g = gamma[c], bt = beta[c];
  for (int n = blockIdx.x; n < NN; n += gridDim.x) {
    float v = outp[(size_t)n * DM + c];
    float s = v, q = v * v;
    for (int m = 32; m; m >>= 1) {
      s += __shfl_xor(s, m, 64);
      q += __shfl_xor(q, m, 64);
    }
    if (l == 0) { red[w] = s; red[4 + w] = q; }
    __syncthreads();
    float S = red[0] + red[1] + red[2] + red[3];
    float Q = red[4] + red[5] + red[6] + red[7];
    __syncthreads();
    float mu = S * (1.f / 256.f);
    float var = Q * (1.f / 256.f) - mu * mu;
    var = fmaxf(var, 0.f);
    float y = (v - mu) * rsqrtf(var + 1e-5f) * g + bt;
    outp[(size_t)n * DM + c] = (y >= 0.f) ? y : pwv * y;
  }
}

extern "C" void kernel_launch(void* const* d_in, const int* in_sizes, int n_in,
                              void* d_out, int out_size, void* d_ws, size_t ws_size,
                              hipStream_t stream) {
  const void* x = d_in[0];
  const void* pos = d_in[1];
  const int* eidx = (const int*)d_in[2];
  const int* tdx = (const int*)d_in[3];
  const int* qdx = (const int*)d_in[4];
  const void* eattr = d_in[5];
  float* outp = (float*)d_out;  // fp32 output (reference returns float32)

  // workspace layout (~170 MB total; proven ws_size >= ~222 MB)
  u16* p_src = (u16*)d_ws;                       // NN*DM bf16 each
  u16* p_mid2 = p_src + (size_t)NN * DM;
  u16* p_mid1 = p_mid2 + (size_t)NN * DM;
  u16* p_dst = p_mid1 + (size_t)NN * DM;
  float* out_n = (float*)(p_dst + (size_t)NN * DM);   // NN*DM fp32 (per-hop)
  float* score = out_n + (size_t)NN * DM;             // NE*8 fp32 (max of E,T,Q)
  float* den = score + (size_t)NE * 8;                // NN*8 fp32
  float* fp = den + (size_t)NN * 8;                   // staged fp32 params
  u32* gmax = (u32*)(fp + TOTALP + 1);
  int* flags = (int*)(gmax + 4);

  // staged param pointers (offsets match g_off order)
  const float* W_src = fp + 0;
  const float* W_dst = fp + 32768;
  const float* W_mid1 = fp + 65536;
  const float* W_mid2 = fp + 98304;
  const float* W_pb = fp + 131072;
  const float* b_pb = fp + 131584;
  const float* W_u = fp + 131840;
  const float* b_u = fp + 142080;
  const float* W_u1 = fp + 142336;
  const float* b_u1 = fp + 152576;
  const float* W_u2 = fp + 152832;
  const float* b_u2 = fp + 163072;
  const float* W_ang = fp + 163328;
  const float* b_ang = fp + 163840;
  const float* W_dih = fp + 164096;
  const float* b_dih = fp + 165632;
  const float* W_1hop = fp + 165888;
  const float* b_1hop = fp + 231424;
  const float* W_2hop = fp + 231680;
  const float* b_2hop = fp + 297216;
  const float* W_3hop = fp + 297472;
  const float* b_3hop = fp + 363008;
  const float* attn2 = fp + 363264;
  const float* attn3 = fp + 363520;
  const float* attn4 = fp + 363776;
  const float* W_res = fp + 364032;
  const float* bias = fp + 396800;
  const float* ln_g = fp + 397056;
  const float* ln_b = fp + 397312;
  const float* prelu = fp + 397568;

  init_detect<<<1, 256, 0, stream>>>((const u32*)eattr, (const u32*)d_in[33], gmax, flags);

  PtrTab tab;
  for (int i = 0; i < 30; ++i) tab.p[i] = d_in[6 + i];
  convert_params<<<512, 256, 0, stream>>>(tab, flags, fp);

  // projections: src(pe0), mid2(pe1), mid1(pe2), dst(pe3)
  proj_kernel<<<NN / 16, 256, 0, stream>>>(x, flags, W_src, p_src, 0);
  proj_kernel<<<NN / 16, 256, 0, stream>>>(x, flags, W_mid2, p_mid2, 1);
  proj_kernel<<<NN / 16, 256, 0, stream>>>(x, flags, W_mid1, p_mid1, 2);
  proj_kernel<<<NN / 16, 256, 0, stream>>>(x, flags, W_dst, p_dst, 3);

  // ---- hop 1 ----
  hipMemsetAsync(den, 0, (size_t)NN * 8 * 4, stream);
  hipMemsetAsync(out_n, 0, (size_t)NN * DM * 4, stream);
  pass1_hop1<<<2048, 256, 0, stream>>>(pos, eidx, eattr, flags, p_mid1, p_dst,
                                       W_pb, b_pb, W_u, b_u, attn2, score, gmax + 0);
  pass2_expden<<<(NE * 8 + 255) / 256, 256, 0, stream>>>(score, eidx + NE, gmax + 0, den, NE);
  pass3_scatter<<<2048, 256, 0, stream>>>(p_mid1, eidx, eidx + NE, score, den, out_n, NE);
  gemm_rowpanel<<<NN / 16, 256, 0, stream>>>(out_n, W_1hop, DM, outp, 0,
                                             x, W_res, FIN, flags, b_1hop, b_2hop, b_3hop, bias);

  // ---- hop 2 ----
  hipMemsetAsync(den, 0, (size_t)NN * 8 * 4, stream);
  hipMemsetAsync(out_n, 0, (size_t)NN * DM * 4, stream);
  pass1_hop2<<<2048, 256, 0, stream>>>(pos, tdx, flags, p_mid2, p_mid1, p_dst,
                                       W_u1, b_u1, W_ang, b_ang, attn3, score, gmax + 1);
  pass2_expden<<<(NT * 8 + 255) / 256, 256, 0, stream>>>(score, tdx + 2 * NT, gmax + 1, den, NT);
  pass3_scatter<<<2048, 256, 0, stream>>>(p_mid2, tdx, tdx + 2 * NT, score, den, out_n, NT);
  gemm_rowpanel<<<NN / 16, 256, 0, stream>>>(out_n, W_2hop, DM, outp, 1,
                                             nullptr, nullptr, 0, flags,
                                             nullptr, nullptr, nullptr, nullptr);

  // ---- hop 3 ----
  hipMemsetAsync(den, 0, (size_t)NN * 8 * 4, stream);
  hipMemsetAsync(out_n, 0, (size_t)NN * DM * 4, stream);
  pass1_hop3<<<2048, 256, 0, stream>>>(pos, qdx, flags, p_src, p_mid2, p_mid1, p_dst,
                                       W_u2, b_u2, W_dih, b_dih, attn4, score, gmax + 2);
  pass2_expden<<<(NQ * 8 + 255) / 256, 256, 0, stream>>>(score, qdx + 3 * NQ, gmax + 2, den, NQ);
  pass3_scatter<<<2048, 256, 0, stream>>>(p_src, qdx, qdx + 3 * NQ, score, den, out_n, NQ);
  gemm_rowpanel<<<NN / 16, 256, 0, stream>>>(out_n, W_3hop, DM, outp, 1,
                                             nullptr, nullptr, 0, flags,
                                             nullptr, nullptr, nullptr, nullptr);

  // ---- layernorm + prelu (in place on d_out) ----
  ln_prelu<<<2048, 256, 0, stream>>>(outp, ln_g, ln_b, prelu);
}

// Round 5
// 3274.770 us; speedup vs baseline: 2.6561x; 2.6561x over previous
//
#include <hip/hip_runtime.h>

#define NN 50000
#define NE 400000
#define NT 300000
#define NQ 200000
#define DM 256
#define FIN 128
#define NRBF 40
#define BETA_RBF 40.0f
#define TOTALP 397569

typedef unsigned int u32;
typedef unsigned short u16;

// ---- bf16 helpers ----
static __device__ __forceinline__ float bf2f(u16 h) {
  return __uint_as_float(((u32)h) << 16);
}
static __device__ __forceinline__ u16 f2bf(float f) {
  u32 u = __float_as_uint(f);
  u32 r = (u + 0x7FFFu + ((u >> 16) & 1u)) >> 16;  // RNE
  return (u16)r;
}
static __device__ __forceinline__ float4 ld4bf(const u16* p) {
  ushort4 v = *reinterpret_cast<const ushort4*>(p);
  return float4{bf2f(v.x), bf2f(v.y), bf2f(v.z), bf2f(v.w)};
}
static __device__ __forceinline__ float4 ld4f(const float* p) {
  return *reinterpret_cast<const float4*>(p);
}
static __device__ __forceinline__ float ldsc(const void* p, int isf, size_t i) {
  return isf ? ((const float*)p)[i] : bf2f(((const u16*)p)[i]);
}
static __device__ __forceinline__ float lk(float t) { return t >= 0.f ? t : 0.2f * t; }
static __device__ __forceinline__ u32 f2o(float f) {
  u32 u = __float_as_uint(f);
  return (u & 0x80000000u) ? ~u : (u | 0x80000000u);
}
static __device__ __forceinline__ float o2f(u32 e) {
  u32 b = (e & 0x80000000u) ? (e & 0x7fffffffu) : ~e;
  return __uint_as_float(b);
}

struct F3 { float x, y, z; };
static __device__ __forceinline__ F3 ldp(const float* pos, int i) {
  return F3{pos[3 * i], pos[3 * i + 1], pos[3 * i + 2]};
}
static __device__ __forceinline__ F3 sub3(F3 a, F3 b) { return F3{a.x - b.x, a.y - b.y, a.z - b.z}; }
static __device__ __forceinline__ float dot3(F3 a, F3 b) { return a.x * b.x + a.y * b.y + a.z * b.z; }
static __device__ __forceinline__ F3 cross3(F3 a, F3 b) {
  return F3{a.y * b.z - a.z * b.y, a.z * b.x - a.x * b.z, a.x * b.y - a.y * b.x};
}
static __device__ __forceinline__ float norm3(F3 v) { return sqrtf(dot3(v, v) + 1e-12f); }
static __device__ __forceinline__ float angle_at(F3 a, F3 m, F3 b) {
  F3 u = sub3(a, m), v = sub3(b, m);
  float c = dot3(u, v) / (norm3(u) * norm3(v) + 1e-12f);
  c = fminf(fmaxf(c, -1.f + 1e-7f), 1.f - 1e-7f);
  return acosf(c);
}
static __device__ __forceinline__ float dihedral_f(F3 p0, F3 p1, F3 p2, F3 p3) {
  F3 b1 = sub3(p1, p0), b2 = sub3(p2, p1), b3 = sub3(p3, p2);
  F3 n1 = cross3(b1, b2), n2 = cross3(b2, b3);
  float nb2 = norm3(b2) + 1e-12f;
  F3 b2n{b2.x / nb2, b2.y / nb2, b2.z / nb2};
  F3 m1 = cross3(n1, b2n);
  return atan2f(dot3(m1, n2), dot3(n1, n2) + 1e-12f);
}

// param staging table: 30 tensors, cumulative offsets
__device__ const int g_off[31] = {
  0, 32768, 65536, 98304, 131072, 131584, 131840, 142080, 142336, 152576,
  152832, 163072, 163328, 163840, 164096, 165632, 165888, 231424, 231680,
  297216, 297472, 363008, 363264, 363520, 363776, 364032, 396800, 397056,
  397312, 397568, 397569};
struct PtrTab { const void* p[30]; };

// ---- init: gmax=-inf; input-dtype + edge_attr-encoding detection ----
__global__ __launch_bounds__(256) void init_detect(const u32* __restrict__ aw,
                                                   const u32* __restrict__ lng,
                                                   u32* __restrict__ gmax,
                                                   int* __restrict__ flags) {
  __shared__ int s_int, s_f32, s_bf;
  if (threadIdx.x == 0) { s_int = 1; s_f32 = 1; s_bf = 1; }
  __syncthreads();
  int li = 1, lf = 1, lb = 1;
  for (int i = threadIdx.x; i < 1024; i += 256) {
    u32 w = aw[i];
    if (w > 1u) li = 0;
    if (w != 0u && w != 0x3F800000u) lf = 0;
    u32 h0 = w & 0xFFFFu, h1 = w >> 16;
    if ((h0 != 0u && h0 != 0x3F80u) || (h1 != 0u && h1 != 0x3F80u)) lb = 0;
  }
  if (!li) atomicAnd(&s_int, 0);
  if (!lf) atomicAnd(&s_f32, 0);
  if (!lb) atomicAnd(&s_bf, 0);
  __syncthreads();
  if (threadIdx.x == 0) {
    flags[0] = s_int ? 0 : (s_f32 ? 2 : (s_bf ? 3 : 1));
    flags[1] = ((lng[0] & 0xFFFFu) == 0x3F80u) ? 0 : 1;  // 1 = fp32 inputs
    gmax[0] = f2o(-INFINITY);
    gmax[1] = f2o(-INFINITY);
    gmax[2] = f2o(-INFINITY);
  }
}

// ---- stage small params to canonical fp32; convert pos ----
__global__ __launch_bounds__(256) void convert_params(PtrTab tab,
                                                      const int* __restrict__ flags,
                                                      float* __restrict__ dst) {
  const int isf = flags[1];
  for (int i = blockIdx.x * blockDim.x + threadIdx.x; i < TOTALP;
       i += gridDim.x * blockDim.x) {
    int t = 0;
    while (i >= g_off[t + 1]) ++t;
    dst[i] = ldsc(tab.p[t], isf, i - g_off[t]);
  }
}
__global__ __launch_bounds__(256) void convert_pos(const void* __restrict__ pos,
                                                   const int* __restrict__ flags,
                                                   float* __restrict__ posf) {
  const int isf = flags[1];
  for (int i = blockIdx.x * blockDim.x + threadIdx.x; i < NN * 3;
       i += gridDim.x * blockDim.x)
    posf[i] = ldsc(pos, isf, i);
}

static __device__ __forceinline__ int read_eattr(const void* p, int flag, int e) {
  if (flag == 1) return ((const unsigned char*)p)[e];
  if (flag == 2) return (((const float*)p)[e] != 0.f);
  if (flag == 3) return (((const u16*)p)[e] != 0);
  return ((const int*)p)[e];
}

// ---- fused 4-way projection, LDS-staged x tile ----
__global__ __launch_bounds__(256) void proj4_kernel(
    const void* __restrict__ x, const int* __restrict__ flags,
    const float* __restrict__ W0, const float* __restrict__ W1,
    const float* __restrict__ W2, const float* __restrict__ W3,
    u16* __restrict__ o0, u16* __restrict__ o1,
    u16* __restrict__ o2, u16* __restrict__ o3) {
  __shared__ float sx[16 * FIN];
  const int c = threadIdx.x;
  const int n0 = blockIdx.x * 16;
  const int isf = flags[1];
#pragma unroll
  for (int i = 0; i < 8; ++i) {
    int l = i * 256 + c;
    sx[l] = ldsc(x, isf, (size_t)n0 * FIN + l);
  }
  __syncthreads();
  float dv = expf(-logf(10000.f) * (float)(c & ~1) / 256.f);
  float p0 = (c & 1) ? cosf(0.f * dv) : sinf(0.f * dv);
  float p1 = (c & 1) ? cosf(1.f * dv) : sinf(1.f * dv);
  float p2 = (c & 1) ? cosf(2.f * dv) : sinf(2.f * dv);
  float p3 = (c & 1) ? cosf(3.f * dv) : sinf(3.f * dv);
  float a0[16], a1[16], a2[16], a3[16];
#pragma unroll
  for (int r = 0; r < 16; ++r) { a0[r] = p0; a1[r] = p1; a2[r] = p2; a3[r] = p3; }
  for (int k = 0; k < FIN; ++k) {
    float w0 = W0[k * DM + c], w1 = W1[k * DM + c];
    float w2 = W2[k * DM + c], w3 = W3[k * DM + c];
#pragma unroll
    for (int r = 0; r < 16; ++r) {
      float xr = sx[r * FIN + k];
      a0[r] = fmaf(xr, w0, a0[r]);
      a1[r] = fmaf(xr, w1, a1[r]);
      a2[r] = fmaf(xr, w2, a2[r]);
      a3[r] = fmaf(xr, w3, a3[r]);
    }
  }
#pragma unroll
  for (int r = 0; r < 16; ++r) {
    size_t off = (size_t)(n0 + r) * DM + c;
    o0[off] = f2bf(a0[r]); o1[off] = f2bf(a1[r]);
    o2[off] = f2bf(a2[r]); o3[off] = f2bf(a3[r]);
  }
}

// ---- CSR build: hist -> scan -> fill ----
__global__ __launch_bounds__(256) void hist_kernel(const int* __restrict__ dst,
                                                   int* __restrict__ deg, int M) {
  for (int i = blockIdx.x * blockDim.x + threadIdx.x; i < M; i += gridDim.x * blockDim.x)
    atomicAdd(&deg[dst[i]], 1);
}
__global__ __launch_bounds__(1024) void scan_kernel(const int* __restrict__ deg,
                                                    int* __restrict__ off,
                                                    int* __restrict__ cur) {
  __shared__ int part[1024];
  const int CH = (NN + 1023) / 1024;
  const int t = threadIdx.x;
  const int base = t * CH;
  int s = 0;
  for (int i = 0; i < CH; ++i) { int idx = base + i; if (idx < NN) s += deg[idx]; }
  part[t] = s;
  __syncthreads();
  for (int d = 1; d < 1024; d <<= 1) {
    int v = (t >= d) ? part[t - d] : 0;
    __syncthreads();
    part[t] += v;
    __syncthreads();
  }
  int run = (t == 0) ? 0 : part[t - 1];
  for (int i = 0; i < CH; ++i) {
    int idx = base + i;
    if (idx < NN) { off[idx] = run; cur[idx] = run; run += deg[idx]; }
  }
  if (t == 1023) off[NN] = run;
}
__global__ __launch_bounds__(256) void fill_kernel(const int* __restrict__ dst,
                                                   int* __restrict__ cur,
                                                   int* __restrict__ eid, int M) {
  for (int i = blockIdx.x * blockDim.x + threadIdx.x; i < M; i += gridDim.x * blockDim.x) {
    int p = atomicAdd(&cur[dst[i]], 1);
    eid[p] = i;
  }
}

// ---- hop1 pass1: one wave per edge, lane = 4 channels ----
__global__ __launch_bounds__(256) void pass1_hop1(
    const float* __restrict__ pos, const int* __restrict__ eidx,
    const void* __restrict__ eattr, const int* __restrict__ flags,
    const u16* __restrict__ p_mid1, const u16* __restrict__ p_dst,
    const float* __restrict__ Wb, const float* __restrict__ bb,
    const float* __restrict__ Wu, const float* __restrict__ bu,
    const float* __restrict__ attn,
    float* __restrict__ score, u32* __restrict__ gmax) {
  const int lane = threadIdx.x & 63;
  const int gw = (blockIdx.x * blockDim.x + threadIdx.x) >> 6;
  const int nw = (gridDim.x * blockDim.x) >> 6;
  const int c4 = lane * 4;
  const int flag = flags[0];
  float4 av = ld4f(attn + c4);
  float4 bbv = ld4f(bb + c4), buv = ld4f(bu + c4);
  float4 bsum{bbv.x + buv.x, bbv.y + buv.y, bbv.z + buv.z, bbv.w + buv.w};
  float4 wb0 = ld4f(Wb + c4), wb1 = ld4f(Wb + DM + c4);
  float rmax = -INFINITY;
  for (int e = gw; e < NE; e += nw) {
    int es = eidx[e], ed = eidx[NE + e];
    F3 Ps = ldp(pos, es), Pd = ldp(pos, ed);
    float d1 = norm3(sub3(Ps, Pd));
    int ea = read_eattr(eattr, flag, e);
    float4 dm = bsum;
    if (ea) {
      float d1c = fminf(fmaxf(d1, 0.05f), 10.f);
      float t = d1c - 0.25f * (float)lane;
      float my = (lane < NRBF) ? expf(-BETA_RBF * t * t) : 0.f;
#pragma unroll
      for (int r = 0; r < NRBF; ++r) {
        float s = __shfl(my, r, 64);
        float4 wv = ld4f(Wu + r * DM + c4);
        dm.x = fmaf(s, wv.x, dm.x); dm.y = fmaf(s, wv.y, dm.y);
        dm.z = fmaf(s, wv.z, dm.z); dm.w = fmaf(s, wv.w, dm.w);
      }
    } else {
      float d1s = d1 * d1;
      dm.x = fmaf(d1, wb0.x, fmaf(d1s, wb1.x, dm.x));
      dm.y = fmaf(d1, wb0.y, fmaf(d1s, wb1.y, dm.y));
      dm.z = fmaf(d1, wb0.z, fmaf(d1s, wb1.z, dm.z));
      dm.w = fmaf(d1, wb0.w, fmaf(d1s, wb1.w, dm.w));
    }
    float4 m = ld4bf(p_mid1 + (size_t)es * DM + c4);
    float4 dd = ld4bf(p_dst + (size_t)ed * DM + c4);
    float s0 = lk((m.x + dd.x) * dm.x);
    float s1 = lk((m.y + dd.y) * dm.y);
    float s2 = lk((m.z + dd.z) * dm.z);
    float s3 = lk((m.w + dd.w) * dm.w);
    float part = av.x * s0 + av.y * s1 + av.z * s2 + av.w * s3;
    part += __shfl_xor(part, 1, 64);
    part += __shfl_xor(part, 2, 64);
    part += __shfl_xor(part, 4, 64);
    if ((lane & 7) == 0) score[(size_t)e * 8 + (lane >> 3)] = part;
    rmax = fmaxf(rmax, part);
  }
  for (int m = 32; m; m >>= 1) rmax = fmaxf(rmax, __shfl_xor(rmax, m, 64));
  if (lane == 0) atomicMax(gmax, f2o(rmax));
}

// ---- hop2 pass1 ----
__global__ __launch_bounds__(256) void pass1_hop2(
    const float* __restrict__ pos, const int* __restrict__ tdx,
    const u16* __restrict__ p_mid2, const u16* __restrict__ p_mid1,
    const u16* __restrict__ p_dst,
    const float* __restrict__ Wu1, const float* __restrict__ bu1,
    const float* __restrict__ Wang, const float* __restrict__ bang,
    const float* __restrict__ attn,
    float* __restrict__ score, u32* __restrict__ gmax) {
  const int lane = threadIdx.x & 63;
  const int gw = (blockIdx.x * blockDim.x + threadIdx.x) >> 6;
  const int nw = (gridDim.x * blockDim.x) >> 6;
  const int c4 = lane * 4;
  float4 av = ld4f(attn + c4);
  float4 b1v = ld4f(bu1 + c4), b2v = ld4f(bang + c4);
  float4 bsum{b1v.x + b2v.x, b1v.y + b2v.y, b1v.z + b2v.z, b1v.w + b2v.w};
  float4 wa0 = ld4f(Wang + c4), wa1 = ld4f(Wang + DM + c4);
  float rmax = -INFINITY;
  for (int t = gw; t < NT; t += nw) {
    int ts = tdx[t], tm = tdx[NT + t], td = tdx[2 * NT + t];
    F3 Ps = ldp(pos, ts), Pm = ldp(pos, tm), Pd = ldp(pos, td);
    float d2 = fminf(fmaxf(norm3(sub3(Ps, Pd)), 0.05f), 10.f);
    float ang = angle_at(Ps, Pm, Pd);
    float angs = ang * ang;
    float4 dm;
    dm.x = fmaf(ang, wa0.x, fmaf(angs, wa1.x, bsum.x));
    dm.y = fmaf(ang, wa0.y, fmaf(angs, wa1.y, bsum.y));
    dm.z = fmaf(ang, wa0.z, fmaf(angs, wa1.z, bsum.z));
    dm.w = fmaf(ang, wa0.w, fmaf(angs, wa1.w, bsum.w));
    float t0 = d2 - 0.25f * (float)lane;
    float my = (lane < NRBF) ? expf(-BETA_RBF * t0 * t0) : 0.f;
#pragma unroll
    for (int r = 0; r < NRBF; ++r) {
      float s = __shfl(my, r, 64);
      float4 wv = ld4f(Wu1 + r * DM + c4);
      dm.x = fmaf(s, wv.x, dm.x); dm.y = fmaf(s, wv.y, dm.y);
      dm.z = fmaf(s, wv.z, dm.z); dm.w = fmaf(s, wv.w, dm.w);
    }
    float4 v0 = ld4bf(p_mid2 + (size_t)ts * DM + c4);
    float4 v1 = ld4bf(p_dst + (size_t)td * DM + c4);
    float4 v2 = ld4bf(p_mid1 + (size_t)tm * DM + c4);
    float s0 = lk((v0.x + v1.x + v2.x) * dm.x);
    float s1 = lk((v0.y + v1.y + v2.y) * dm.y);
    float s2 = lk((v0.z + v1.z + v2.z) * dm.z);
    float s3 = lk((v0.w + v1.w + v2.w) * dm.w);
    float part = av.x * s0 + av.y * s1 + av.z * s2 + av.w * s3;
    part += __shfl_xor(part, 1, 64);
    part += __shfl_xor(part, 2, 64);
    part += __shfl_xor(part, 4, 64);
    if ((lane & 7) == 0) score[(size_t)t * 8 + (lane >> 3)] = part;
    rmax = fmaxf(rmax, part);
  }
  for (int m = 32; m; m >>= 1) rmax = fmaxf(rmax, __shfl_xor(rmax, m, 64));
  if (lane == 0) atomicMax(gmax, f2o(rmax));
}

// ---- hop3 pass1 ----
__global__ __launch_bounds__(256) void pass1_hop3(
    const float* __restrict__ pos, const int* __restrict__ qdx,
    const u16* __restrict__ p_src, const u16* __restrict__ p_mid2,
    const u16* __restrict__ p_mid1, const u16* __restrict__ p_dst,
    const float* __restrict__ Wu2, const float* __restrict__ bu2,
    const float* __restrict__ Wd, const float* __restrict__ bd,
    const float* __restrict__ attn,
    float* __restrict__ score, u32* __restrict__ gmax) {
  const int lane = threadIdx.x & 63;
  const int gw = (blockIdx.x * blockDim.x + threadIdx.x) >> 6;
  const int nw = (gridDim.x * blockDim.x) >> 6;
  const int c4 = lane * 4;
  float4 av = ld4f(attn + c4);
  float4 b1v = ld4f(bu2 + c4), b2v = ld4f(bd + c4);
  float4 bsum{b1v.x + b2v.x, b1v.y + b2v.y, b1v.z + b2v.z, b1v.w + b2v.w};
  float4 wd0 = ld4f(Wd + c4), wd1 = ld4f(Wd + DM + c4), wd2 = ld4f(Wd + 2 * DM + c4);
  float4 wd3 = ld4f(Wd + 3 * DM + c4), wd4 = ld4f(Wd + 4 * DM + c4), wd5 = ld4f(Wd + 5 * DM + c4);
  float rmax = -INFINITY;
  for (int q = gw; q < NQ; q += nw) {
    int qs = qdx[q], q2 = qdx[NQ + q], q1 = qdx[2 * NQ + q], qd = qdx[3 * NQ + q];
    F3 P0 = ldp(pos, qs), P1 = ldp(pos, q2), P2 = ldp(pos, q1), P3 = ldp(pos, qd);
    float d3 = fminf(fmaxf(norm3(sub3(P0, P3)), 0.05f), 10.f);
    float a1f = angle_at(P0, P1, P2);
    float a2f = angle_at(P1, P2, P3);
    float dh = dihedral_f(P0, P1, P2, P3);
    float f0 = a1f, f1 = a1f * a1f, f2 = a2f, f3 = a2f * a2f, f4 = dh, f5 = dh * dh;
    float4 dm;
    dm.x = bsum.x + f0 * wd0.x + f1 * wd1.x + f2 * wd2.x + f3 * wd3.x + f4 * wd4.x + f5 * wd5.x;
    dm.y = bsum.y + f0 * wd0.y + f1 * wd1.y + f2 * wd2.y + f3 * wd3.y + f4 * wd4.y + f5 * wd5.y;
    dm.z = bsum.z + f0 * wd0.z + f1 * wd1.z + f2 * wd2.z + f3 * wd3.z + f4 * wd4.z + f5 * wd5.z;
    dm.w = bsum.w + f0 * wd0.w + f1 * wd1.w + f2 * wd2.w + f3 * wd3.w + f4 * wd4.w + f5 * wd5.w;
    float t0 = d3 - 0.25f * (float)lane;
    float my = (lane < NRBF) ? expf(-BETA_RBF * t0 * t0) : 0.f;
#pragma unroll
    for (int r = 0; r < NRBF; ++r) {
      float s = __shfl(my, r, 64);
      float4 wv = ld4f(Wu2 + r * DM + c4);
      dm.x = fmaf(s, wv.x, dm.x); dm.y = fmaf(s, wv.y, dm.y);
      dm.z = fmaf(s, wv.z, dm.z); dm.w = fmaf(s, wv.w, dm.w);
    }
    float4 v0 = ld4bf(p_src + (size_t)qs * DM + c4);
    float4 v1 = ld4bf(p_mid2 + (size_t)q2 * DM + c4);
    float4 v2 = ld4bf(p_mid1 + (size_t)q1 * DM + c4);
    float4 v3 = ld4bf(p_dst + (size_t)qd * DM + c4);
    float s0 = lk((v0.x + v1.x + v2.x + v3.x) * dm.x);
    float s1 = lk((v0.y + v1.y + v2.y + v3.y) * dm.y);
    float s2 = lk((v0.z + v1.z + v2.z + v3.z) * dm.z);
    float s3 = lk((v0.w + v1.w + v2.w + v3.w) * dm.w);
    float part = av.x * s0 + av.y * s1 + av.z * s2 + av.w * s3;
    part += __shfl_xor(part, 1, 64);
    part += __shfl_xor(part, 2, 64);
    part += __shfl_xor(part, 4, 64);
    if ((lane & 7) == 0) score[(size_t)q * 8 + (lane >> 3)] = part;
    rmax = fmaxf(rmax, part);
  }
  for (int m = 32; m; m >>= 1) rmax = fmaxf(rmax, __shfl_xor(rmax, m, 64));
  if (lane == 0) atomicMax(gmax, f2o(rmax));
}

// ---- fused softmax + aggregate: one wave per dst node (atomic-free) ----
__global__ __launch_bounds__(256) void gather_kernel(
    const u16* __restrict__ srcvec, const int* __restrict__ gidx,
    const float* __restrict__ score, const int* __restrict__ off,
    const int* __restrict__ eid, const u32* __restrict__ gmax,
    float* __restrict__ outn) {
  const int wid = (blockIdx.x * blockDim.x + threadIdx.x) >> 6;
  if (wid >= NN) return;
  const int lane = threadIdx.x & 63;
  const int h = lane >> 3;
  const int c4 = lane * 4;
  const float g = o2f(*gmax);
  const int s0 = off[wid], s1 = off[wid + 1];
  float4 vacc{0.f, 0.f, 0.f, 0.f};
  float wsum = 0.f;
  for (int j = s0; j < s1; ++j) {
    int e = eid[j];
    int s = gidx[e];
    float ev = expf(score[(size_t)e * 8 + h] - g);
    wsum += ev;
    float4 v = ld4bf(srcvec + (size_t)s * DM + c4);
    vacc.x = fmaf(ev, v.x, vacc.x);
    vacc.y = fmaf(ev, v.y, vacc.y);
    vacc.z = fmaf(ev, v.z, vacc.z);
    vacc.w = fmaf(ev, v.w, vacc.w);
  }
  float inv = 1.f / (wsum + 1e-16f);
  float* op = outn + (size_t)wid * DM + c4;
  op[0] = vacc.x * inv;
  op[1] = vacc.y * inv;
  op[2] = vacc.z * inv;
  op[3] = vacc.w * inv;
}

// ---- output GEMM into fp32 d_out, LDS-staged A (+X2) ----
__global__ __launch_bounds__(256) void gemm_lds(
    const float* __restrict__ A, const float* __restrict__ W, int K,
    float* __restrict__ outp, int accumulate,
    const void* __restrict__ X2, const float* __restrict__ W2, int K2,
    const int* __restrict__ flags,
    const float* __restrict__ b0, const float* __restrict__ b1,
    const float* __restrict__ b2, const float* __restrict__ b3) {
  __shared__ float sm[16 * DM + 16 * FIN];  // 24 KB
  const int c = threadIdx.x;
  const int n0 = blockIdx.x * 16;
  for (int i = c; i < 16 * K; i += 256) sm[i] = A[(size_t)n0 * K + i];
  float* sm2 = sm + 16 * K;
  if (X2) {
    const int isf = flags[1];
    for (int i = c; i < 16 * K2; i += 256) sm2[i] = ldsc(X2, isf, (size_t)n0 * K2 + i);
  }
  __syncthreads();
  float acc[16];
  if (accumulate) {
#pragma unroll
    for (int r = 0; r < 16; ++r) acc[r] = outp[(size_t)(n0 + r) * DM + c];
  } else {
    float base = b0[c] + b1[c] + b2[c] + b3[c];
#pragma unroll
    for (int r = 0; r < 16; ++r) acc[r] = base;
  }
  for (int k = 0; k < K; ++k) {
    float wv = W[k * DM + c];
#pragma unroll
    for (int r = 0; r < 16; ++r) acc[r] = fmaf(sm[r * K + k], wv, acc[r]);
  }
  if (X2) {
    for (int k = 0; k < K2; ++k) {
      float wv = W2[k * DM + c];
#pragma unroll
      for (int r = 0; r < 16; ++r) acc[r] = fmaf(sm2[r * K2 + k], wv, acc[r]);
    }
  }
#pragma unroll
  for (int r = 0; r < 16; ++r) outp[(size_t)(n0 + r) * DM + c] = acc[r];
}

// ---- LayerNorm + PReLU, in place on fp32 d_out ----
__global__ __launch_bounds__(256) void ln_prelu(float* __restrict__ outp,
                                                const float* __restrict__ gamma,
                                                const float* __restrict__ beta,
                                                const float* __restrict__ pw) {
  __shared__ float red[8];
  const int c = threadIdx.x, w = c >> 6, l = c & 63;
  float pwv = pw[0];
  float g = gamma[c], bt = beta[c];
  for (int n = blockIdx.x; n < NN; n += gridDim.x) {
    float v = outp[(size_t)n * DM + c];
    float s = v, q = v * v;
    for (int m = 32; m; m >>= 1) {
      s += __shfl_xor(s, m, 64);
      q += __shfl_xor(q, m, 64);
    }
    if (l == 0) { red[w] = s; red[4 + w] = q; }
    __syncthreads();
    float S = red[0] + red[1] + red[2] + red[3];
    float Q = red[4] + red[5] + red[6] + red[7];
    __syncthreads();
    float mu = S * (1.f / 256.f);
    float var = Q * (1.f / 256.f) - mu * mu;
    var = fmaxf(var, 0.f);
    float y = (v - mu) * rsqrtf(var + 1e-5f) * g + bt;
    outp[(size_t)n * DM + c] = (y >= 0.f) ? y : pwv * y;
  }
}

extern "C" void kernel_launch(void* const* d_in, const int* in_sizes, int n_in,
                              void* d_out, int out_size, void* d_ws, size_t ws_size,
                              hipStream_t stream) {
  const void* x = d_in[0];
  const void* pos = d_in[1];
  const int* eidx = (const int*)d_in[2];
  const int* tdx = (const int*)d_in[3];
  const int* qdx = (const int*)d_in[4];
  const void* eattr = d_in[5];
  float* outp = (float*)d_out;

  // workspace layout (~171 MB)
  u16* p_src = (u16*)d_ws;
  u16* p_mid2 = p_src + (size_t)NN * DM;
  u16* p_mid1 = p_mid2 + (size_t)NN * DM;
  u16* p_dst = p_mid1 + (size_t)NN * DM;
  float* out_n = (float*)(p_dst + (size_t)NN * DM);   // NN*DM fp32
  float* score = out_n + (size_t)NN * DM;             // NE*8 fp32 (max)
  float* posf = score + (size_t)NE * 8;               // NN*3 fp32
  float* fp = posf + (size_t)NN * 3;                  // staged fp32 params
  int* deg = (int*)(fp + TOTALP + 3);
  int* off = deg + NN;       // NN+1
  int* cur = off + NN + 1;
  int* eid = cur + NN;       // NE max
  u32* gmax = (u32*)(eid + NE);
  int* flags = (int*)(gmax + 4);

  const float* W_src = fp + 0;
  const float* W_dst = fp + 32768;
  const float* W_mid1 = fp + 65536;
  const float* W_mid2 = fp + 98304;
  const float* W_pb = fp + 131072;
  const float* b_pb = fp + 131584;
  const float* W_u = fp + 131840;
  const float* b_u = fp + 142080;
  const float* W_u1 = fp + 142336;
  const float* b_u1 = fp + 152576;
  const float* W_u2 = fp + 152832;
  const float* b_u2 = fp + 163072;
  const float* W_ang = fp + 163328;
  const float* b_ang = fp + 163840;
  const float* W_dih = fp + 164096;
  const float* b_dih = fp + 165632;
  const float* W_1hop = fp + 165888;
  const float* b_1hop = fp + 231424;
  const float* W_2hop = fp + 231680;
  const float* b_2hop = fp + 297216;
  const float* W_3hop = fp + 297472;
  const float* b_3hop = fp + 363008;
  const float* attn2 = fp + 363264;
  const float* attn3 = fp + 363520;
  const float* attn4 = fp + 363776;
  const float* W_res = fp + 364032;
  const float* bias = fp + 396800;
  const float* ln_g = fp + 397056;
  const float* ln_b = fp + 397312;
  const float* prelu = fp + 397568;

  init_detect<<<1, 256, 0, stream>>>((const u32*)eattr, (const u32*)d_in[33], gmax, flags);

  PtrTab tab;
  for (int i = 0; i < 30; ++i) tab.p[i] = d_in[6 + i];
  convert_params<<<512, 256, 0, stream>>>(tab, flags, fp);
  convert_pos<<<587, 256, 0, stream>>>(pos, flags, posf);

  proj4_kernel<<<NN / 16, 256, 0, stream>>>(x, flags, W_src, W_mid2, W_mid1, W_dst,
                                            p_src, p_mid2, p_mid1, p_dst);

  // ---- hop 1 ----
  hipMemsetAsync(deg, 0, (size_t)NN * 4, stream);
  hist_kernel<<<1024, 256, 0, stream>>>(eidx + NE, deg, NE);
  scan_kernel<<<1, 1024, 0, stream>>>(deg, off, cur);
  fill_kernel<<<1024, 256, 0, stream>>>(eidx + NE, cur, eid, NE);
  pass1_hop1<<<2048, 256, 0, stream>>>(posf, eidx, eattr, flags, p_mid1, p_dst,
                                       W_pb, b_pb, W_u, b_u, attn2, score, gmax + 0);
  gather_kernel<<<(NN + 3) / 4, 256, 0, stream>>>(p_mid1, eidx, score, off, eid,
                                                  gmax + 0, out_n);
  gemm_lds<<<NN / 16, 256, 0, stream>>>(out_n, W_1hop, DM, outp, 0,
                                        x, W_res, FIN, flags, b_1hop, b_2hop, b_3hop, bias);

  // ---- hop 2 ----
  hipMemsetAsync(deg, 0, (size_t)NN * 4, stream);
  hist_kernel<<<1024, 256, 0, stream>>>(tdx + 2 * NT, deg, NT);
  scan_kernel<<<1, 1024, 0, stream>>>(deg, off, cur);
  fill_kernel<<<1024, 256, 0, stream>>>(tdx + 2 * NT, cur, eid, NT);
  pass1_hop2<<<2048, 256, 0, stream>>>(posf, tdx, p_mid2, p_mid1, p_dst,
                                       W_u1, b_u1, W_ang, b_ang, attn3, score, gmax + 1);
  gather_kernel<<<(NN + 3) / 4, 256, 0, stream>>>(p_mid2, tdx, score, off, eid,
                                                  gmax + 1, out_n);
  gemm_lds<<<NN / 16, 256, 0, stream>>>(out_n, W_2hop, DM, outp, 1,
                                        nullptr, nullptr, 0, flags,
                                        nullptr, nullptr, nullptr, nullptr);

  // ---- hop 3 ----
  hipMemsetAsync(deg, 0, (size_t)NN * 4, stream);
  hist_kernel<<<1024, 256, 0, stream>>>(qdx + 3 * NQ, deg, NQ);
  scan_kernel<<<1, 1024, 0, stream>>>(deg, off, cur);
  fill_kernel<<<1024, 256, 0, stream>>>(qdx + 3 * NQ, cur, eid, NQ);
  pass1_hop3<<<2048, 256, 0, stream>>>(posf, qdx, p_src, p_mid2, p_mid1, p_dst,
                                       W_u2, b_u2, W_dih, b_dih, attn4, score, gmax + 2);
  gather_kernel<<<(NN + 3) / 4, 256, 0, stream>>>(p_src, qdx, score, off, eid,
                                                  gmax + 2, out_n);
  gemm_lds<<<NN / 16, 256, 0, stream>>>(out_n, W_3hop, DM, outp, 1,
                                        nullptr, nullptr, 0, flags,
                                        nullptr, nullptr, nullptr, nullptr);

  // ---- layernorm + prelu ----
  ln_prelu<<<2048, 256, 0, stream>>>(outp, ln_g, ln_b, prelu);
}

// Round 6
// 2313.820 us; speedup vs baseline: 3.7592x; 1.4153x over previous
//
#include <hip/hip_runtime.h>

#define NN 50000
#define NE 400000
#define NT 300000
#define NQ 200000
#define DM 256
#define FIN 128
#define NRBF 40
#define BETA_RBF 40.0f
#define TOTALP 397569

typedef unsigned int u32;
typedef unsigned short u16;

// ---- bf16 helpers ----
static __device__ __forceinline__ float bf2f(u16 h) {
  return __uint_as_float(((u32)h) << 16);
}
static __device__ __forceinline__ u16 f2bf(float f) {
  u32 u = __float_as_uint(f);
  u32 r = (u + 0x7FFFu + ((u >> 16) & 1u)) >> 16;  // RNE
  return (u16)r;
}
static __device__ __forceinline__ float4 ld4bf(const u16* p) {
  ushort4 v = *reinterpret_cast<const ushort4*>(p);
  return float4{bf2f(v.x), bf2f(v.y), bf2f(v.z), bf2f(v.w)};
}
static __device__ __forceinline__ float4 ld4f(const float* p) {
  return *reinterpret_cast<const float4*>(p);
}
static __device__ __forceinline__ float ldsc(const void* p, int isf, size_t i) {
  return isf ? ((const float*)p)[i] : bf2f(((const u16*)p)[i]);
}
static __device__ __forceinline__ float lk(float t) { return t >= 0.f ? t : 0.2f * t; }
static __device__ __forceinline__ u32 f2o(float f) {
  u32 u = __float_as_uint(f);
  return (u & 0x80000000u) ? ~u : (u | 0x80000000u);
}
static __device__ __forceinline__ float o2f(u32 e) {
  u32 b = (e & 0x80000000u) ? (e & 0x7fffffffu) : ~e;
  return __uint_as_float(b);
}

struct F3 { float x, y, z; };
static __device__ __forceinline__ F3 ldp(const float* pos, int i) {
  return F3{pos[3 * i], pos[3 * i + 1], pos[3 * i + 2]};
}
static __device__ __forceinline__ F3 sub3(F3 a, F3 b) { return F3{a.x - b.x, a.y - b.y, a.z - b.z}; }
static __device__ __forceinline__ float dot3(F3 a, F3 b) { return a.x * b.x + a.y * b.y + a.z * b.z; }
static __device__ __forceinline__ F3 cross3(F3 a, F3 b) {
  return F3{a.y * b.z - a.z * b.y, a.z * b.x - a.x * b.z, a.x * b.y - a.y * b.x};
}
static __device__ __forceinline__ float norm3(F3 v) { return sqrtf(dot3(v, v) + 1e-12f); }
static __device__ __forceinline__ float angle_at(F3 a, F3 m, F3 b) {
  F3 u = sub3(a, m), v = sub3(b, m);
  float c = dot3(u, v) / (norm3(u) * norm3(v) + 1e-12f);
  c = fminf(fmaxf(c, -1.f + 1e-7f), 1.f - 1e-7f);
  return acosf(c);
}
static __device__ __forceinline__ float dihedral_f(F3 p0, F3 p1, F3 p2, F3 p3) {
  F3 b1 = sub3(p1, p0), b2 = sub3(p2, p1), b3 = sub3(p3, p2);
  F3 n1 = cross3(b1, b2), n2 = cross3(b2, b3);
  float nb2 = norm3(b2) + 1e-12f;
  F3 b2n{b2.x / nb2, b2.y / nb2, b2.z / nb2};
  F3 m1 = cross3(n1, b2n);
  return atan2f(dot3(m1, n2), dot3(n1, n2) + 1e-12f);
}

// RBF matvec, 8-term window: exp(-40(d-c)^2) < 4e-18 outside |d-c|>=1.0,
// so centers outside [j-3, j+4] (j=floor(4d)) contribute nothing at fp32.
static __device__ __forceinline__ float4 rbf_acc(float d, const float* __restrict__ Wu,
                                                 float4 dm, int c4) {
  int j = (int)floorf(d * 4.0f) - 3;
  j = (j < 0) ? 0 : ((j > NRBF - 8) ? (NRBF - 8) : j);
  const float* base = Wu + j * DM + c4;
  float t0 = d - 0.25f * (float)j;
#pragma unroll
  for (int k = 0; k < 8; ++k) {
    float t = t0 - 0.25f * (float)k;
    float s = __expf(-BETA_RBF * t * t);
    float4 wv = ld4f(base + k * DM);
    dm.x = fmaf(s, wv.x, dm.x);
    dm.y = fmaf(s, wv.y, dm.y);
    dm.z = fmaf(s, wv.z, dm.z);
    dm.w = fmaf(s, wv.w, dm.w);
  }
  return dm;
}

// param staging table: 30 tensors, cumulative offsets
__device__ const int g_off[31] = {
  0, 32768, 65536, 98304, 131072, 131584, 131840, 142080, 142336, 152576,
  152832, 163072, 163328, 163840, 164096, 165632, 165888, 231424, 231680,
  297216, 297472, 363008, 363264, 363520, 363776, 364032, 396800, 397056,
  397312, 397568, 397569};
struct PtrTab { const void* p[30]; };

// ---- init: gmax=-inf; input-dtype + edge_attr-encoding detection ----
__global__ __launch_bounds__(256) void init_detect(const u32* __restrict__ aw,
                                                   const u32* __restrict__ lng,
                                                   u32* __restrict__ gmax,
                                                   int* __restrict__ flags) {
  __shared__ int s_int, s_f32, s_bf;
  if (threadIdx.x == 0) { s_int = 1; s_f32 = 1; s_bf = 1; }
  __syncthreads();
  int li = 1, lf = 1, lb = 1;
  for (int i = threadIdx.x; i < 1024; i += 256) {
    u32 w = aw[i];
    if (w > 1u) li = 0;
    if (w != 0u && w != 0x3F800000u) lf = 0;
    u32 h0 = w & 0xFFFFu, h1 = w >> 16;
    if ((h0 != 0u && h0 != 0x3F80u) || (h1 != 0u && h1 != 0x3F80u)) lb = 0;
  }
  if (!li) atomicAnd(&s_int, 0);
  if (!lf) atomicAnd(&s_f32, 0);
  if (!lb) atomicAnd(&s_bf, 0);
  __syncthreads();
  if (threadIdx.x == 0) {
    flags[0] = s_int ? 0 : (s_f32 ? 2 : (s_bf ? 3 : 1));
    flags[1] = ((lng[0] & 0xFFFFu) == 0x3F80u) ? 0 : 1;  // 1 = fp32 inputs
    gmax[0] = f2o(-INFINITY);
    gmax[1] = f2o(-INFINITY);
    gmax[2] = f2o(-INFINITY);
  }
}

// ---- stage small params to canonical fp32; convert pos ----
__global__ __launch_bounds__(256) void convert_params(PtrTab tab,
                                                      const int* __restrict__ flags,
                                                      float* __restrict__ dst) {
  const int isf = flags[1];
  for (int i = blockIdx.x * blockDim.x + threadIdx.x; i < TOTALP;
       i += gridDim.x * blockDim.x) {
    int t = 0;
    while (i >= g_off[t + 1]) ++t;
    dst[i] = ldsc(tab.p[t], isf, i - g_off[t]);
  }
}
__global__ __launch_bounds__(256) void convert_pos(const void* __restrict__ pos,
                                                   const int* __restrict__ flags,
                                                   float* __restrict__ posf) {
  const int isf = flags[1];
  for (int i = blockIdx.x * blockDim.x + threadIdx.x; i < NN * 3;
       i += gridDim.x * blockDim.x)
    posf[i] = ldsc(pos, isf, i);
}

static __device__ __forceinline__ int read_eattr(const void* p, int flag, int e) {
  if (flag == 1) return ((const unsigned char*)p)[e];
  if (flag == 2) return (((const float*)p)[e] != 0.f);
  if (flag == 3) return (((const u16*)p)[e] != 0);
  return ((const int*)p)[e];
}

// ---- fused 4-way projection, LDS-staged x tile ----
__global__ __launch_bounds__(256) void proj4_kernel(
    const void* __restrict__ x, const int* __restrict__ flags,
    const float* __restrict__ W0, const float* __restrict__ W1,
    const float* __restrict__ W2, const float* __restrict__ W3,
    u16* __restrict__ o0, u16* __restrict__ o1,
    u16* __restrict__ o2, u16* __restrict__ o3) {
  __shared__ float sx[16 * FIN];
  const int c = threadIdx.x;
  const int n0 = blockIdx.x * 16;
  const int isf = flags[1];
#pragma unroll
  for (int i = 0; i < 8; ++i) {
    int l = i * 256 + c;
    sx[l] = ldsc(x, isf, (size_t)n0 * FIN + l);
  }
  __syncthreads();
  float dv = expf(-logf(10000.f) * (float)(c & ~1) / 256.f);
  float p0 = (c & 1) ? cosf(0.f * dv) : sinf(0.f * dv);
  float p1 = (c & 1) ? cosf(1.f * dv) : sinf(1.f * dv);
  float p2 = (c & 1) ? cosf(2.f * dv) : sinf(2.f * dv);
  float p3 = (c & 1) ? cosf(3.f * dv) : sinf(3.f * dv);
  float a0[16], a1[16], a2[16], a3[16];
#pragma unroll
  for (int r = 0; r < 16; ++r) { a0[r] = p0; a1[r] = p1; a2[r] = p2; a3[r] = p3; }
  for (int k = 0; k < FIN; ++k) {
    float w0 = W0[k * DM + c], w1 = W1[k * DM + c];
    float w2 = W2[k * DM + c], w3 = W3[k * DM + c];
#pragma unroll
    for (int r = 0; r < 16; ++r) {
      float xr = sx[r * FIN + k];
      a0[r] = fmaf(xr, w0, a0[r]);
      a1[r] = fmaf(xr, w1, a1[r]);
      a2[r] = fmaf(xr, w2, a2[r]);
      a3[r] = fmaf(xr, w3, a3[r]);
    }
  }
#pragma unroll
  for (int r = 0; r < 16; ++r) {
    size_t off = (size_t)(n0 + r) * DM + c;
    o0[off] = f2bf(a0[r]); o1[off] = f2bf(a1[r]);
    o2[off] = f2bf(a2[r]); o3[off] = f2bf(a3[r]);
  }
}

// ---- CSR build: hist -> scan -> fill ----
__global__ __launch_bounds__(256) void hist_kernel(const int* __restrict__ dst,
                                                   int* __restrict__ deg, int M) {
  for (int i = blockIdx.x * blockDim.x + threadIdx.x; i < M; i += gridDim.x * blockDim.x)
    atomicAdd(&deg[dst[i]], 1);
}
__global__ __launch_bounds__(1024) void scan_kernel(const int* __restrict__ deg,
                                                    int* __restrict__ off,
                                                    int* __restrict__ cur) {
  __shared__ int part[1024];
  const int CH = (NN + 1023) / 1024;
  const int t = threadIdx.x;
  const int base = t * CH;
  int s = 0;
  for (int i = 0; i < CH; ++i) { int idx = base + i; if (idx < NN) s += deg[idx]; }
  part[t] = s;
  __syncthreads();
  for (int d = 1; d < 1024; d <<= 1) {
    int v = (t >= d) ? part[t - d] : 0;
    __syncthreads();
    part[t] += v;
    __syncthreads();
  }
  int run = (t == 0) ? 0 : part[t - 1];
  for (int i = 0; i < CH; ++i) {
    int idx = base + i;
    if (idx < NN) { off[idx] = run; cur[idx] = run; run += deg[idx]; }
  }
  if (t == 1023) off[NN] = run;
}
__global__ __launch_bounds__(256) void fill_kernel(const int* __restrict__ dst,
                                                   int* __restrict__ cur,
                                                   int* __restrict__ eid, int M) {
  for (int i = blockIdx.x * blockDim.x + threadIdx.x; i < M; i += gridDim.x * blockDim.x) {
    int p = atomicAdd(&cur[dst[i]], 1);
    eid[p] = i;
  }
}

// ---- hop1 pass1: one wave per edge, lane = 4 channels ----
__global__ __launch_bounds__(256, 4) void pass1_hop1(
    const float* __restrict__ pos, const int* __restrict__ eidx,
    const void* __restrict__ eattr, const int* __restrict__ flags,
    const u16* __restrict__ p_mid1, const u16* __restrict__ p_dst,
    const float* __restrict__ Wb, const float* __restrict__ bb,
    const float* __restrict__ Wu, const float* __restrict__ bu,
    const float* __restrict__ attn,
    float* __restrict__ score, u32* __restrict__ gmax) {
  const int lane = threadIdx.x & 63;
  const int gw = (blockIdx.x * blockDim.x + threadIdx.x) >> 6;
  const int nw = (gridDim.x * blockDim.x) >> 6;
  const int c4 = lane * 4;
  const int flag = flags[0];
  float4 av = ld4f(attn + c4);
  float4 bbv = ld4f(bb + c4), buv = ld4f(bu + c4);
  float4 bsum{bbv.x + buv.x, bbv.y + buv.y, bbv.z + buv.z, bbv.w + buv.w};
  float4 wb0 = ld4f(Wb + c4), wb1 = ld4f(Wb + DM + c4);
  float rmax = -INFINITY;
  for (int e = gw; e < NE; e += nw) {
    int es = eidx[e], ed = eidx[NE + e];
    F3 Ps = ldp(pos, es), Pd = ldp(pos, ed);
    float d1 = norm3(sub3(Ps, Pd));
    int ea = read_eattr(eattr, flag, e);
    float4 dm = bsum;
    if (ea) {
      float d1c = fminf(fmaxf(d1, 0.05f), 10.f);
      dm = rbf_acc(d1c, Wu, dm, c4);
    } else {
      float d1s = d1 * d1;
      dm.x = fmaf(d1, wb0.x, fmaf(d1s, wb1.x, dm.x));
      dm.y = fmaf(d1, wb0.y, fmaf(d1s, wb1.y, dm.y));
      dm.z = fmaf(d1, wb0.z, fmaf(d1s, wb1.z, dm.z));
      dm.w = fmaf(d1, wb0.w, fmaf(d1s, wb1.w, dm.w));
    }
    float4 m = ld4bf(p_mid1 + (size_t)es * DM + c4);
    float4 dd = ld4bf(p_dst + (size_t)ed * DM + c4);
    float s0 = lk((m.x + dd.x) * dm.x);
    float s1 = lk((m.y + dd.y) * dm.y);
    float s2 = lk((m.z + dd.z) * dm.z);
    float s3 = lk((m.w + dd.w) * dm.w);
    float part = av.x * s0 + av.y * s1 + av.z * s2 + av.w * s3;
    part += __shfl_xor(part, 1, 64);
    part += __shfl_xor(part, 2, 64);
    part += __shfl_xor(part, 4, 64);
    if ((lane & 7) == 0) score[(size_t)e * 8 + (lane >> 3)] = part;
    rmax = fmaxf(rmax, part);
  }
  for (int m = 32; m; m >>= 1) rmax = fmaxf(rmax, __shfl_xor(rmax, m, 64));
  if (lane == 0) atomicMax(gmax, f2o(rmax));
}

// ---- hop2 pass1 ----
__global__ __launch_bounds__(256, 4) void pass1_hop2(
    const float* __restrict__ pos, const int* __restrict__ tdx,
    const u16* __restrict__ p_mid2, const u16* __restrict__ p_mid1,
    const u16* __restrict__ p_dst,
    const float* __restrict__ Wu1, const float* __restrict__ bu1,
    const float* __restrict__ Wang, const float* __restrict__ bang,
    const float* __restrict__ attn,
    float* __restrict__ score, u32* __restrict__ gmax) {
  const int lane = threadIdx.x & 63;
  const int gw = (blockIdx.x * blockDim.x + threadIdx.x) >> 6;
  const int nw = (gridDim.x * blockDim.x) >> 6;
  const int c4 = lane * 4;
  float4 av = ld4f(attn + c4);
  float4 b1v = ld4f(bu1 + c4), b2v = ld4f(bang + c4);
  float4 bsum{b1v.x + b2v.x, b1v.y + b2v.y, b1v.z + b2v.z, b1v.w + b2v.w};
  float4 wa0 = ld4f(Wang + c4), wa1 = ld4f(Wang + DM + c4);
  float rmax = -INFINITY;
  for (int t = gw; t < NT; t += nw) {
    int ts = tdx[t], tm = tdx[NT + t], td = tdx[2 * NT + t];
    F3 Ps = ldp(pos, ts), Pm = ldp(pos, tm), Pd = ldp(pos, td);
    float d2 = fminf(fmaxf(norm3(sub3(Ps, Pd)), 0.05f), 10.f);
    float ang = angle_at(Ps, Pm, Pd);
    float angs = ang * ang;
    float4 dm;
    dm.x = fmaf(ang, wa0.x, fmaf(angs, wa1.x, bsum.x));
    dm.y = fmaf(ang, wa0.y, fmaf(angs, wa1.y, bsum.y));
    dm.z = fmaf(ang, wa0.z, fmaf(angs, wa1.z, bsum.z));
    dm.w = fmaf(ang, wa0.w, fmaf(angs, wa1.w, bsum.w));
    dm = rbf_acc(d2, Wu1, dm, c4);
    float4 v0 = ld4bf(p_mid2 + (size_t)ts * DM + c4);
    float4 v1 = ld4bf(p_dst + (size_t)td * DM + c4);
    float4 v2 = ld4bf(p_mid1 + (size_t)tm * DM + c4);
    float s0 = lk((v0.x + v1.x + v2.x) * dm.x);
    float s1 = lk((v0.y + v1.y + v2.y) * dm.y);
    float s2 = lk((v0.z + v1.z + v2.z) * dm.z);
    float s3 = lk((v0.w + v1.w + v2.w) * dm.w);
    float part = av.x * s0 + av.y * s1 + av.z * s2 + av.w * s3;
    part += __shfl_xor(part, 1, 64);
    part += __shfl_xor(part, 2, 64);
    part += __shfl_xor(part, 4, 64);
    if ((lane & 7) == 0) score[(size_t)t * 8 + (lane >> 3)] = part;
    rmax = fmaxf(rmax, part);
  }
  for (int m = 32; m; m >>= 1) rmax = fmaxf(rmax, __shfl_xor(rmax, m, 64));
  if (lane == 0) atomicMax(gmax, f2o(rmax));
}

// ---- hop3 pass1 ----
__global__ __launch_bounds__(256, 4) void pass1_hop3(
    const float* __restrict__ pos, const int* __restrict__ qdx,
    const u16* __restrict__ p_src, const u16* __restrict__ p_mid2,
    const u16* __restrict__ p_mid1, const u16* __restrict__ p_dst,
    const float* __restrict__ Wu2, const float* __restrict__ bu2,
    const float* __restrict__ Wd, const float* __restrict__ bd,
    const float* __restrict__ attn,
    float* __restrict__ score, u32* __restrict__ gmax) {
  const int lane = threadIdx.x & 63;
  const int gw = (blockIdx.x * blockDim.x + threadIdx.x) >> 6;
  const int nw = (gridDim.x * blockDim.x) >> 6;
  const int c4 = lane * 4;
  float4 av = ld4f(attn + c4);
  float4 b1v = ld4f(bu2 + c4), b2v = ld4f(bd + c4);
  float4 bsum{b1v.x + b2v.x, b1v.y + b2v.y, b1v.z + b2v.z, b1v.w + b2v.w};
  float4 wd0 = ld4f(Wd + c4), wd1 = ld4f(Wd + DM + c4), wd2 = ld4f(Wd + 2 * DM + c4);
  float4 wd3 = ld4f(Wd + 3 * DM + c4), wd4 = ld4f(Wd + 4 * DM + c4), wd5 = ld4f(Wd + 5 * DM + c4);
  float rmax = -INFINITY;
  for (int q = gw; q < NQ; q += nw) {
    int qs = qdx[q], q2 = qdx[NQ + q], q1 = qdx[2 * NQ + q], qd = qdx[3 * NQ + q];
    F3 P0 = ldp(pos, qs), P1 = ldp(pos, q2), P2 = ldp(pos, q1), P3 = ldp(pos, qd);
    float d3 = fminf(fmaxf(norm3(sub3(P0, P3)), 0.05f), 10.f);
    float a1f = angle_at(P0, P1, P2);
    float a2f = angle_at(P1, P2, P3);
    float dh = dihedral_f(P0, P1, P2, P3);
    float f0 = a1f, f1 = a1f * a1f, f2 = a2f, f3 = a2f * a2f, f4 = dh, f5 = dh * dh;
    float4 dm;
    dm.x = bsum.x + f0 * wd0.x + f1 * wd1.x + f2 * wd2.x + f3 * wd3.x + f4 * wd4.x + f5 * wd5.x;
    dm.y = bsum.y + f0 * wd0.y + f1 * wd1.y + f2 * wd2.y + f3 * wd3.y + f4 * wd4.y + f5 * wd5.y;
    dm.z = bsum.z + f0 * wd0.z + f1 * wd1.z + f2 * wd2.z + f3 * wd3.z + f4 * wd4.z + f5 * wd5.z;
    dm.w = bsum.w + f0 * wd0.w + f1 * wd1.w + f2 * wd2.w + f3 * wd3.w + f4 * wd4.w + f5 * wd5.w;
    dm = rbf_acc(d3, Wu2, dm, c4);
    float4 v0 = ld4bf(p_src + (size_t)qs * DM + c4);
    float4 v1 = ld4bf(p_mid2 + (size_t)q2 * DM + c4);
    float4 v2 = ld4bf(p_mid1 + (size_t)q1 * DM + c4);
    float4 v3 = ld4bf(p_dst + (size_t)qd * DM + c4);
    float s0 = lk((v0.x + v1.x + v2.x + v3.x) * dm.x);
    float s1 = lk((v0.y + v1.y + v2.y + v3.y) * dm.y);
    float s2 = lk((v0.z + v1.z + v2.z + v3.z) * dm.z);
    float s3 = lk((v0.w + v1.w + v2.w + v3.w) * dm.w);
    float part = av.x * s0 + av.y * s1 + av.z * s2 + av.w * s3;
    part += __shfl_xor(part, 1, 64);
    part += __shfl_xor(part, 2, 64);
    part += __shfl_xor(part, 4, 64);
    if ((lane & 7) == 0) score[(size_t)q * 8 + (lane >> 3)] = part;
    rmax = fmaxf(rmax, part);
  }
  for (int m = 32; m; m >>= 1) rmax = fmaxf(rmax, __shfl_xor(rmax, m, 64));
  if (lane == 0) atomicMax(gmax, f2o(rmax));
}

// ---- fused softmax + aggregate: one wave per dst node (atomic-free) ----
__global__ __launch_bounds__(256) void gather_kernel(
    const u16* __restrict__ srcvec, const int* __restrict__ gidx,
    const float* __restrict__ score, const int* __restrict__ off,
    const int* __restrict__ eid, const u32* __restrict__ gmax,
    float* __restrict__ outn) {
  const int wid = (blockIdx.x * blockDim.x + threadIdx.x) >> 6;
  if (wid >= NN) return;
  const int lane = threadIdx.x & 63;
  const int h = lane >> 3;
  const int c4 = lane * 4;
  const float g = o2f(*gmax);
  const int s0 = off[wid], s1 = off[wid + 1];
  float4 vacc{0.f, 0.f, 0.f, 0.f};
  float wsum = 0.f;
  for (int j = s0; j < s1; ++j) {
    int e = eid[j];
    int s = gidx[e];
    float ev = expf(score[(size_t)e * 8 + h] - g);
    wsum += ev;
    float4 v = ld4bf(srcvec + (size_t)s * DM + c4);
    vacc.x = fmaf(ev, v.x, vacc.x);
    vacc.y = fmaf(ev, v.y, vacc.y);
    vacc.z = fmaf(ev, v.z, vacc.z);
    vacc.w = fmaf(ev, v.w, vacc.w);
  }
  float inv = 1.f / (wsum + 1e-16f);
  float* op = outn + (size_t)wid * DM + c4;
  op[0] = vacc.x * inv;
  op[1] = vacc.y * inv;
  op[2] = vacc.z * inv;
  op[3] = vacc.w * inv;
}

// ---- output GEMM into fp32 d_out, LDS-staged A (+X2) ----
__global__ __launch_bounds__(256) void gemm_lds(
    const float* __restrict__ A, const float* __restrict__ W, int K,
    float* __restrict__ outp, int accumulate,
    const void* __restrict__ X2, const float* __restrict__ W2, int K2,
    const int* __restrict__ flags,
    const float* __restrict__ b0, const float* __restrict__ b1,
    const float* __restrict__ b2, const float* __restrict__ b3) {
  __shared__ float sm[16 * DM + 16 * FIN];  // 24 KB
  const int c = threadIdx.x;
  const int n0 = blockIdx.x * 16;
  for (int i = c; i < 16 * K; i += 256) sm[i] = A[(size_t)n0 * K + i];
  float* sm2 = sm + 16 * K;
  if (X2) {
    const int isf = flags[1];
    for (int i = c; i < 16 * K2; i += 256) sm2[i] = ldsc(X2, isf, (size_t)n0 * K2 + i);
  }
  __syncthreads();
  float acc[16];
  if (accumulate) {
#pragma unroll
    for (int r = 0; r < 16; ++r) acc[r] = outp[(size_t)(n0 + r) * DM + c];
  } else {
    float base = b0[c] + b1[c] + b2[c] + b3[c];
#pragma unroll
    for (int r = 0; r < 16; ++r) acc[r] = base;
  }
  for (int k = 0; k < K; ++k) {
    float wv = W[k * DM + c];
#pragma unroll
    for (int r = 0; r < 16; ++r) acc[r] = fmaf(sm[r * K + k], wv, acc[r]);
  }
  if (X2) {
    for (int k = 0; k < K2; ++k) {
      float wv = W2[k * DM + c];
#pragma unroll
      for (int r = 0; r < 16; ++r) acc[r] = fmaf(sm2[r * K2 + k], wv, acc[r]);
    }
  }
#pragma unroll
  for (int r = 0; r < 16; ++r) outp[(size_t)(n0 + r) * DM + c] = acc[r];
}

// ---- LayerNorm + PReLU, in place on fp32 d_out ----
__global__ __launch_bounds__(256) void ln_prelu(float* __restrict__ outp,
                                                const float* __restrict__ gamma,
                                                const float* __restrict__ beta,
                                                const float* __restrict__ pw) {
  __shared__ float red[8];
  const int c = threadIdx.x, w = c >> 6, l = c & 63;
  float pwv = pw[0];
  float g = gamma[c], bt = beta[c];
  for (int n = blockIdx.x; n < NN; n += gridDim.x) {
    float v = outp[(size_t)n * DM + c];
    float s = v, q = v * v;
    for (int m = 32; m; m >>= 1) {
      s += __shfl_xor(s, m, 64);
      q += __shfl_xor(q, m, 64);
    }
    if (l == 0) { red[w] = s; red[4 + w] = q; }
    __syncthreads();
    float S = red[0] + red[1] + red[2] + red[3];
    float Q = red[4] + red[5] + red[6] + red[7];
    __syncthreads();
    float mu = S * (1.f / 256.f);
    float var = Q * (1.f / 256.f) - mu * mu;
    var = fmaxf(var, 0.f);
    float y = (v - mu) * rsqrtf(var + 1e-5f) * g + bt;
    outp[(size_t)n * DM + c] = (y >= 0.f) ? y : pwv * y;
  }
}

extern "C" void kernel_launch(void* const* d_in, const int* in_sizes, int n_in,
                              void* d_out, int out_size, void* d_ws, size_t ws_size,
                              hipStream_t stream) {
  const void* x = d_in[0];
  const void* pos = d_in[1];
  const int* eidx = (const int*)d_in[2];
  const int* tdx = (const int*)d_in[3];
  const int* qdx = (const int*)d_in[4];
  const void* eattr = d_in[5];
  float* outp = (float*)d_out;

  // workspace layout (~171 MB)
  u16* p_src = (u16*)d_ws;
  u16* p_mid2 = p_src + (size_t)NN * DM;
  u16* p_mid1 = p_mid2 + (size_t)NN * DM;
  u16* p_dst = p_mid1 + (size_t)NN * DM;
  float* out_n = (float*)(p_dst + (size_t)NN * DM);   // NN*DM fp32
  float* score = out_n + (size_t)NN * DM;             // NE*8 fp32 (max)
  float* posf = score + (size_t)NE * 8;               // NN*3 fp32
  float* fp = posf + (size_t)NN * 3;                  // staged fp32 params
  int* deg = (int*)(fp + TOTALP + 3);
  int* off = deg + NN;       // NN+1
  int* cur = off + NN + 1;
  int* eid = cur + NN;       // NE max
  u32* gmax = (u32*)(eid + NE);
  int* flags = (int*)(gmax + 4);

  const float* W_src = fp + 0;
  const float* W_dst = fp + 32768;
  const float* W_mid1 = fp + 65536;
  const float* W_mid2 = fp + 98304;
  const float* W_pb = fp + 131072;
  const float* b_pb = fp + 131584;
  const float* W_u = fp + 131840;
  const float* b_u = fp + 142080;
  const float* W_u1 = fp + 142336;
  const float* b_u1 = fp + 152576;
  const float* W_u2 = fp + 152832;
  const float* b_u2 = fp + 163072;
  const float* W_ang = fp + 163328;
  const float* b_ang = fp + 163840;
  const float* W_dih = fp + 164096;
  const float* b_dih = fp + 165632;
  const float* W_1hop = fp + 165888;
  const float* b_1hop = fp + 231424;
  const float* W_2hop = fp + 231680;
  const float* b_2hop = fp + 297216;
  const float* W_3hop = fp + 297472;
  const float* b_3hop = fp + 363008;
  const float* attn2 = fp + 363264;
  const float* attn3 = fp + 363520;
  const float* attn4 = fp + 363776;
  const float* W_res = fp + 364032;
  const float* bias = fp + 396800;
  const float* ln_g = fp + 397056;
  const float* ln_b = fp + 397312;
  const float* prelu = fp + 397568;

  init_detect<<<1, 256, 0, stream>>>((const u32*)eattr, (const u32*)d_in[33], gmax, flags);

  PtrTab tab;
  for (int i = 0; i < 30; ++i) tab.p[i] = d_in[6 + i];
  convert_params<<<512, 256, 0, stream>>>(tab, flags, fp);
  convert_pos<<<587, 256, 0, stream>>>(pos, flags, posf);

  proj4_kernel<<<NN / 16, 256, 0, stream>>>(x, flags, W_src, W_mid2, W_mid1, W_dst,
                                            p_src, p_mid2, p_mid1, p_dst);

  // ---- hop 1 ----
  hipMemsetAsync(deg, 0, (size_t)NN * 4, stream);
  hist_kernel<<<1024, 256, 0, stream>>>(eidx + NE, deg, NE);
  scan_kernel<<<1, 1024, 0, stream>>>(deg, off, cur);
  fill_kernel<<<1024, 256, 0, stream>>>(eidx + NE, cur, eid, NE);
  pass1_hop1<<<2048, 256, 0, stream>>>(posf, eidx, eattr, flags, p_mid1, p_dst,
                                       W_pb, b_pb, W_u, b_u, attn2, score, gmax + 0);
  gather_kernel<<<(NN + 3) / 4, 256, 0, stream>>>(p_mid1, eidx, score, off, eid,
                                                  gmax + 0, out_n);
  gemm_lds<<<NN / 16, 256, 0, stream>>>(out_n, W_1hop, DM, outp, 0,
                                        x, W_res, FIN, flags, b_1hop, b_2hop, b_3hop, bias);

  // ---- hop 2 ----
  hipMemsetAsync(deg, 0, (size_t)NN * 4, stream);
  hist_kernel<<<1024, 256, 0, stream>>>(tdx + 2 * NT, deg, NT);
  scan_kernel<<<1, 1024, 0, stream>>>(deg, off, cur);
  fill_kernel<<<1024, 256, 0, stream>>>(tdx + 2 * NT, cur, eid, NT);
  pass1_hop2<<<2048, 256, 0, stream>>>(posf, tdx, p_mid2, p_mid1, p_dst,
                                       W_u1, b_u1, W_ang, b_ang, attn3, score, gmax + 1);
  gather_kernel<<<(NN + 3) / 4, 256, 0, stream>>>(p_mid2, tdx, score, off, eid,
                                                  gmax + 1, out_n);
  gemm_lds<<<NN / 16, 256, 0, stream>>>(out_n, W_2hop, DM, outp, 1,
                                        nullptr, nullptr, 0, flags,
                                        nullptr, nullptr, nullptr, nullptr);

  // ---- hop 3 ----
  hipMemsetAsync(deg, 0, (size_t)NN * 4, stream);
  hist_kernel<<<1024, 256, 0, stream>>>(qdx + 3 * NQ, deg, NQ);
  scan_kernel<<<1, 1024, 0, stream>>>(deg, off, cur);
  fill_kernel<<<1024, 256, 0, stream>>>(qdx + 3 * NQ, cur, eid, NQ);
  pass1_hop3<<<2048, 256, 0, stream>>>(posf, qdx, p_src, p_mid2, p_mid1, p_dst,
                                       W_u2, b_u2, W_dih, b_dih, attn4, score, gmax + 2);
  gather_kernel<<<(NN + 3) / 4, 256, 0, stream>>>(p_src, qdx, score, off, eid,
                                                  gmax + 2, out_n);
  gemm_lds<<<NN / 16, 256, 0, stream>>>(out_n, W_3hop, DM, outp, 1,
                                        nullptr, nullptr, 0, flags,
                                        nullptr, nullptr, nullptr, nullptr);

  // ---- layernorm + prelu ----
  ln_prelu<<<2048, 256, 0, stream>>>(outp, ln_g, ln_b, prelu);
}

// Round 7
// 1882.519 us; speedup vs baseline: 4.6205x; 1.2291x over previous
//
#include <hip/hip_runtime.h>

#define NN 50000
#define NE 400000
#define NT 300000
#define NQ 200000
#define DM 256
#define FIN 128
#define NRBF 40
#define BETA_RBF 40.0f
#define TOTALP 397569

typedef unsigned int u32;
typedef unsigned short u16;

// ---- bf16 helpers ----
static __device__ __forceinline__ float bf2f(u16 h) {
  return __uint_as_float(((u32)h) << 16);
}
static __device__ __forceinline__ u16 f2bf(float f) {
  u32 u = __float_as_uint(f);
  u32 r = (u + 0x7FFFu + ((u >> 16) & 1u)) >> 16;  // RNE
  return (u16)r;
}
static __device__ __forceinline__ float4 ld4bf(const u16* p) {
  ushort4 v = *reinterpret_cast<const ushort4*>(p);
  return float4{bf2f(v.x), bf2f(v.y), bf2f(v.z), bf2f(v.w)};
}
static __device__ __forceinline__ float4 ld4f(const float* p) {
  return *reinterpret_cast<const float4*>(p);
}
static __device__ __forceinline__ float ldsc(const void* p, int isf, size_t i) {
  return isf ? ((const float*)p)[i] : bf2f(((const u16*)p)[i]);
}
static __device__ __forceinline__ float lk(float t) { return t >= 0.f ? t : 0.2f * t; }
static __device__ __forceinline__ u32 f2o(float f) {
  u32 u = __float_as_uint(f);
  return (u & 0x80000000u) ? ~u : (u | 0x80000000u);
}
static __device__ __forceinline__ float o2f(u32 e) {
  u32 b = (e & 0x80000000u) ? (e & 0x7fffffffu) : ~e;
  return __uint_as_float(b);
}

struct F3 { float x, y, z; };
static __device__ __forceinline__ F3 ldp(const float* pos, int i) {
  return F3{pos[3 * i], pos[3 * i + 1], pos[3 * i + 2]};
}
static __device__ __forceinline__ F3 sub3(F3 a, F3 b) { return F3{a.x - b.x, a.y - b.y, a.z - b.z}; }
static __device__ __forceinline__ float dot3(F3 a, F3 b) { return a.x * b.x + a.y * b.y + a.z * b.z; }
static __device__ __forceinline__ F3 cross3(F3 a, F3 b) {
  return F3{a.y * b.z - a.z * b.y, a.z * b.x - a.x * b.z, a.x * b.y - a.y * b.x};
}
static __device__ __forceinline__ float norm3(F3 v) { return sqrtf(dot3(v, v) + 1e-12f); }
static __device__ __forceinline__ float angle_at(F3 a, F3 m, F3 b) {
  F3 u = sub3(a, m), v = sub3(b, m);
  float c = dot3(u, v) / (norm3(u) * norm3(v) + 1e-12f);
  c = fminf(fmaxf(c, -1.f + 1e-7f), 1.f - 1e-7f);
  return acosf(c);
}
static __device__ __forceinline__ float dihedral_f(F3 p0, F3 p1, F3 p2, F3 p3) {
  F3 b1 = sub3(p1, p0), b2 = sub3(p2, p1), b3 = sub3(p3, p2);
  F3 n1 = cross3(b1, b2), n2 = cross3(b2, b3);
  float nb2 = norm3(b2) + 1e-12f;
  F3 b2n{b2.x / nb2, b2.y / nb2, b2.z / nb2};
  F3 m1 = cross3(n1, b2n);
  return atan2f(dot3(m1, n2), dot3(n1, n2) + 1e-12f);
}

// RBF matvec, 8-term window: exp(-40(d-c)^2) < 4e-18 outside |d-c|>=1.0.
static __device__ __forceinline__ float4 rbf_acc(float d, const float* __restrict__ Wu,
                                                 float4 dm, int c4) {
  int j = (int)floorf(d * 4.0f) - 3;
  j = (j < 0) ? 0 : ((j > NRBF - 8) ? (NRBF - 8) : j);
  const float* base = Wu + j * DM + c4;
  float t0 = d - 0.25f * (float)j;
#pragma unroll
  for (int k = 0; k < 8; ++k) {
    float t = t0 - 0.25f * (float)k;
    float s = __expf(-BETA_RBF * t * t);
    float4 wv = ld4f(base + k * DM);
    dm.x = fmaf(s, wv.x, dm.x);
    dm.y = fmaf(s, wv.y, dm.y);
    dm.z = fmaf(s, wv.z, dm.z);
    dm.w = fmaf(s, wv.w, dm.w);
  }
  return dm;
}

// param staging table: 30 tensors, cumulative offsets
__device__ const int g_off[31] = {
  0, 32768, 65536, 98304, 131072, 131584, 131840, 142080, 142336, 152576,
  152832, 163072, 163328, 163840, 164096, 165632, 165888, 231424, 231680,
  297216, 297472, 363008, 363264, 363520, 363776, 364032, 396800, 397056,
  397312, 397568, 397569};
struct PtrTab { const void* p[30]; };

// ---- init ----
__global__ __launch_bounds__(256) void init_detect(const u32* __restrict__ aw,
                                                   const u32* __restrict__ lng,
                                                   u32* __restrict__ gmax,
                                                   int* __restrict__ flags) {
  __shared__ int s_int, s_f32, s_bf;
  if (threadIdx.x == 0) { s_int = 1; s_f32 = 1; s_bf = 1; }
  __syncthreads();
  int li = 1, lf = 1, lb = 1;
  for (int i = threadIdx.x; i < 1024; i += 256) {
    u32 w = aw[i];
    if (w > 1u) li = 0;
    if (w != 0u && w != 0x3F800000u) lf = 0;
    u32 h0 = w & 0xFFFFu, h1 = w >> 16;
    if ((h0 != 0u && h0 != 0x3F80u) || (h1 != 0u && h1 != 0x3F80u)) lb = 0;
  }
  if (!li) atomicAnd(&s_int, 0);
  if (!lf) atomicAnd(&s_f32, 0);
  if (!lb) atomicAnd(&s_bf, 0);
  __syncthreads();
  if (threadIdx.x == 0) {
    flags[0] = s_int ? 0 : (s_f32 ? 2 : (s_bf ? 3 : 1));
    flags[1] = ((lng[0] & 0xFFFFu) == 0x3F80u) ? 0 : 1;  // 1 = fp32 inputs
    gmax[0] = f2o(-INFINITY);
    gmax[1] = f2o(-INFINITY);
    gmax[2] = f2o(-INFINITY);
  }
}

__global__ __launch_bounds__(256) void convert_params(PtrTab tab,
                                                      const int* __restrict__ flags,
                                                      float* __restrict__ dst) {
  const int isf = flags[1];
  for (int i = blockIdx.x * blockDim.x + threadIdx.x; i < TOTALP;
       i += gridDim.x * blockDim.x) {
    int t = 0;
    while (i >= g_off[t + 1]) ++t;
    dst[i] = ldsc(tab.p[t], isf, i - g_off[t]);
  }
}
__global__ __launch_bounds__(256) void convert_pos(const void* __restrict__ pos,
                                                   const int* __restrict__ flags,
                                                   float* __restrict__ posf) {
  const int isf = flags[1];
  for (int i = blockIdx.x * blockDim.x + threadIdx.x; i < NN * 3;
       i += gridDim.x * blockDim.x)
    posf[i] = ldsc(pos, isf, i);
}

static __device__ __forceinline__ int read_eattr(const void* p, int flag, int e) {
  if (flag == 1) return ((const unsigned char*)p)[e];
  if (flag == 2) return (((const float*)p)[e] != 0.f);
  if (flag == 3) return (((const u16*)p)[e] != 0);
  return ((const int*)p)[e];
}

// ---- fused 4-way projection ----
__global__ __launch_bounds__(256) void proj4_kernel(
    const void* __restrict__ x, const int* __restrict__ flags,
    const float* __restrict__ W0, const float* __restrict__ W1,
    const float* __restrict__ W2, const float* __restrict__ W3,
    u16* __restrict__ o0, u16* __restrict__ o1,
    u16* __restrict__ o2, u16* __restrict__ o3) {
  __shared__ float sx[16 * FIN];
  const int c = threadIdx.x;
  const int n0 = blockIdx.x * 16;
  const int isf = flags[1];
#pragma unroll
  for (int i = 0; i < 8; ++i) {
    int l = i * 256 + c;
    sx[l] = ldsc(x, isf, (size_t)n0 * FIN + l);
  }
  __syncthreads();
  float dv = expf(-logf(10000.f) * (float)(c & ~1) / 256.f);
  float p0 = (c & 1) ? cosf(0.f * dv) : sinf(0.f * dv);
  float p1 = (c & 1) ? cosf(1.f * dv) : sinf(1.f * dv);
  float p2 = (c & 1) ? cosf(2.f * dv) : sinf(2.f * dv);
  float p3 = (c & 1) ? cosf(3.f * dv) : sinf(3.f * dv);
  float a0[16], a1[16], a2[16], a3[16];
#pragma unroll
  for (int r = 0; r < 16; ++r) { a0[r] = p0; a1[r] = p1; a2[r] = p2; a3[r] = p3; }
  for (int k = 0; k < FIN; ++k) {
    float w0 = W0[k * DM + c], w1 = W1[k * DM + c];
    float w2 = W2[k * DM + c], w3 = W3[k * DM + c];
#pragma unroll
    for (int r = 0; r < 16; ++r) {
      float xr = sx[r * FIN + k];
      a0[r] = fmaf(xr, w0, a0[r]);
      a1[r] = fmaf(xr, w1, a1[r]);
      a2[r] = fmaf(xr, w2, a2[r]);
      a3[r] = fmaf(xr, w3, a3[r]);
    }
  }
#pragma unroll
  for (int r = 0; r < 16; ++r) {
    size_t off = (size_t)(n0 + r) * DM + c;
    o0[off] = f2bf(a0[r]); o1[off] = f2bf(a1[r]);
    o2[off] = f2bf(a2[r]); o3[off] = f2bf(a3[r]);
  }
}

// ---- fused CSR build over the 3 hops ----
__global__ __launch_bounds__(256) void hist_all(const int* __restrict__ ed,
                                                const int* __restrict__ td,
                                                const int* __restrict__ qd,
                                                int* __restrict__ deg) {
  const int M = NE + NT + NQ;
  for (int i = blockIdx.x * blockDim.x + threadIdx.x; i < M; i += gridDim.x * blockDim.x) {
    if (i < NE) atomicAdd(&deg[ed[i]], 1);
    else if (i < NE + NT) atomicAdd(&deg[NN + td[i - NE]], 1);
    else atomicAdd(&deg[2 * NN + qd[i - NE - NT]], 1);
  }
}
__global__ __launch_bounds__(1024) void scan_all(const int* __restrict__ degall,
                                                 int* __restrict__ offall,
                                                 int* __restrict__ curall) {
  __shared__ int part[1024];
  const int b = blockIdx.x;
  const int* deg = degall + (size_t)b * NN;
  int* off = offall + (size_t)b * (NN + 1);
  int* cur = curall + (size_t)b * NN;
  const int CH = (NN + 1023) / 1024;
  const int t = threadIdx.x;
  const int base = t * CH;
  int s = 0;
  for (int i = 0; i < CH; ++i) { int idx = base + i; if (idx < NN) s += deg[idx]; }
  part[t] = s;
  __syncthreads();
  for (int d = 1; d < 1024; d <<= 1) {
    int v = (t >= d) ? part[t - d] : 0;
    __syncthreads();
    part[t] += v;
    __syncthreads();
  }
  int run = (t == 0) ? 0 : part[t - 1];
  for (int i = 0; i < CH; ++i) {
    int idx = base + i;
    if (idx < NN) { off[idx] = run; cur[idx] = run; run += deg[idx]; }
  }
  if (t == 1023) off[NN] = run;
}
__global__ __launch_bounds__(256) void fill_all(const int* __restrict__ ed,
                                                const int* __restrict__ td,
                                                const int* __restrict__ qd,
                                                int* __restrict__ cur,
                                                int* __restrict__ eid) {
  const int M = NE + NT + NQ;
  for (int i = blockIdx.x * blockDim.x + threadIdx.x; i < M; i += gridDim.x * blockDim.x) {
    if (i < NE) {
      int p = atomicAdd(&cur[ed[i]], 1);
      eid[p] = i;
    } else if (i < NE + NT) {
      int il = i - NE;
      int p = atomicAdd(&cur[NN + td[il]], 1);
      eid[NE + p] = il;
    } else {
      int il = i - NE - NT;
      int p = atomicAdd(&cur[2 * NN + qd[il]], 1);
      eid[NE + NT + p] = il;
    }
  }
}

// ---- fused pass1 (3 hops, block-partitioned, prefetch-pipelined) ----
// blocks [0,2048) hop1, [2048,3584) hop2, [3584,4608) hop3
__global__ __launch_bounds__(256, 4) void pass1_all(
    const float* __restrict__ pos,
    const int* __restrict__ eidx, const int* __restrict__ tdx, const int* __restrict__ qdx,
    const void* __restrict__ eattr, const int* __restrict__ flags,
    const u16* __restrict__ p_src, const u16* __restrict__ p_mid2,
    const u16* __restrict__ p_mid1, const u16* __restrict__ p_dst,
    const float* __restrict__ fp,
    float* __restrict__ score1, float* __restrict__ score2, float* __restrict__ score3,
    u32* __restrict__ gmax) {
  const int lane = threadIdx.x & 63;
  const int c4 = lane * 4;
  const int bid = blockIdx.x;
  float rmax = -INFINITY;

  if (bid < 2048) {
    // ================= hop 1 =================
    const int nw = 2048 * 4;
    const int gw = ((bid * 256 + (int)threadIdx.x) >> 6);
    const int flag = flags[0];
    const float* Wb = fp + 131072;
    const float* bb = fp + 131584;
    const float* Wu = fp + 131840;
    const float* bu = fp + 142080;
    const float* attn = fp + 363264;
    float4 av = ld4f(attn + c4);
    float4 bbv = ld4f(bb + c4), buv = ld4f(bu + c4);
    float4 bsum{bbv.x + buv.x, bbv.y + buv.y, bbv.z + buv.z, bbv.w + buv.w};
    float4 wb0 = ld4f(Wb + c4), wb1 = ld4f(Wb + DM + c4);
    int e = gw;
    int es = 0, ed = 0, ea = 0;
    F3 Ps{0, 0, 0}, Pd{0, 0, 0};
    if (e < NE) {
      es = eidx[e]; ed = eidx[NE + e]; ea = read_eattr(eattr, flag, e);
      Ps = ldp(pos, es); Pd = ldp(pos, ed);
    }
    while (e < NE) {
      int en = e + nw;
      int nes = 0, ned = 0, nea = 0;
      F3 nPs{0, 0, 0}, nPd{0, 0, 0};
      if (en < NE) {
        nes = eidx[en]; ned = eidx[NE + en]; nea = read_eattr(eattr, flag, en);
        nPs = ldp(pos, nes); nPd = ldp(pos, ned);
      }
      float d1 = norm3(sub3(Ps, Pd));
      float4 dm = bsum;
      if (ea) {
        float d1c = fminf(fmaxf(d1, 0.05f), 10.f);
        dm = rbf_acc(d1c, Wu, dm, c4);
      } else {
        float d1s = d1 * d1;
        dm.x = fmaf(d1, wb0.x, fmaf(d1s, wb1.x, dm.x));
        dm.y = fmaf(d1, wb0.y, fmaf(d1s, wb1.y, dm.y));
        dm.z = fmaf(d1, wb0.z, fmaf(d1s, wb1.z, dm.z));
        dm.w = fmaf(d1, wb0.w, fmaf(d1s, wb1.w, dm.w));
      }
      float4 m = ld4bf(p_mid1 + (size_t)es * DM + c4);
      float4 dd = ld4bf(p_dst + (size_t)ed * DM + c4);
      float s0 = lk((m.x + dd.x) * dm.x);
      float s1 = lk((m.y + dd.y) * dm.y);
      float s2 = lk((m.z + dd.z) * dm.z);
      float s3 = lk((m.w + dd.w) * dm.w);
      float part = av.x * s0 + av.y * s1 + av.z * s2 + av.w * s3;
      part += __shfl_xor(part, 1, 64);
      part += __shfl_xor(part, 2, 64);
      part += __shfl_xor(part, 4, 64);
      if ((lane & 7) == 0) score1[(size_t)e * 8 + (lane >> 3)] = part;
      rmax = fmaxf(rmax, part);
      e = en; es = nes; ed = ned; ea = nea; Ps = nPs; Pd = nPd;
    }
    for (int m = 32; m; m >>= 1) rmax = fmaxf(rmax, __shfl_xor(rmax, m, 64));
    if (lane == 0) atomicMax(gmax + 0, f2o(rmax));
  } else if (bid < 3584) {
    // ================= hop 2 =================
    const int nw = 1536 * 4;
    const int gw = (((bid - 2048) * 256 + (int)threadIdx.x) >> 6);
    const float* Wu1 = fp + 142336;
    const float* bu1 = fp + 152576;
    const float* Wang = fp + 163328;
    const float* bang = fp + 163840;
    const float* attn = fp + 363520;
    float4 av = ld4f(attn + c4);
    float4 b1v = ld4f(bu1 + c4), b2v = ld4f(bang + c4);
    float4 bsum{b1v.x + b2v.x, b1v.y + b2v.y, b1v.z + b2v.z, b1v.w + b2v.w};
    float4 wa0 = ld4f(Wang + c4), wa1 = ld4f(Wang + DM + c4);
    int t = gw;
    int ts = 0, tm = 0, td = 0;
    F3 Ps{0, 0, 0}, Pm{0, 0, 0}, Pd{0, 0, 0};
    if (t < NT) {
      ts = tdx[t]; tm = tdx[NT + t]; td = tdx[2 * NT + t];
      Ps = ldp(pos, ts); Pm = ldp(pos, tm); Pd = ldp(pos, td);
    }
    while (t < NT) {
      int tn = t + nw;
      int nts = 0, ntm = 0, ntd = 0;
      F3 nPs{0, 0, 0}, nPm{0, 0, 0}, nPd{0, 0, 0};
      if (tn < NT) {
        nts = tdx[tn]; ntm = tdx[NT + tn]; ntd = tdx[2 * NT + tn];
        nPs = ldp(pos, nts); nPm = ldp(pos, ntm); nPd = ldp(pos, ntd);
      }
      float d2 = fminf(fmaxf(norm3(sub3(Ps, Pd)), 0.05f), 10.f);
      float ang = angle_at(Ps, Pm, Pd);
      float angs = ang * ang;
      float4 dm;
      dm.x = fmaf(ang, wa0.x, fmaf(angs, wa1.x, bsum.x));
      dm.y = fmaf(ang, wa0.y, fmaf(angs, wa1.y, bsum.y));
      dm.z = fmaf(ang, wa0.z, fmaf(angs, wa1.z, bsum.z));
      dm.w = fmaf(ang, wa0.w, fmaf(angs, wa1.w, bsum.w));
      dm = rbf_acc(d2, Wu1, dm, c4);
      float4 v0 = ld4bf(p_mid2 + (size_t)ts * DM + c4);
      float4 v1 = ld4bf(p_dst + (size_t)td * DM + c4);
      float4 v2 = ld4bf(p_mid1 + (size_t)tm * DM + c4);
      float s0 = lk((v0.x + v1.x + v2.x) * dm.x);
      float s1 = lk((v0.y + v1.y + v2.y) * dm.y);
      float s2 = lk((v0.z + v1.z + v2.z) * dm.z);
      float s3 = lk((v0.w + v1.w + v2.w) * dm.w);
      float part = av.x * s0 + av.y * s1 + av.z * s2 + av.w * s3;
      part += __shfl_xor(part, 1, 64);
      part += __shfl_xor(part, 2, 64);
      part += __shfl_xor(part, 4, 64);
      if ((lane & 7) == 0) score2[(size_t)t * 8 + (lane >> 3)] = part;
      rmax = fmaxf(rmax, part);
      t = tn; ts = nts; tm = ntm; td = ntd; Ps = nPs; Pm = nPm; Pd = nPd;
    }
    for (int m = 32; m; m >>= 1) rmax = fmaxf(rmax, __shfl_xor(rmax, m, 64));
    if (lane == 0) atomicMax(gmax + 1, f2o(rmax));
  } else {
    // ================= hop 3 =================
    const int nw = 1024 * 4;
    const int gw = (((bid - 3584) * 256 + (int)threadIdx.x) >> 6);
    const float* Wu2 = fp + 152832;
    const float* bu2 = fp + 163072;
    const float* Wd = fp + 164096;
    const float* bd = fp + 165632;
    const float* attn = fp + 363776;
    float4 av = ld4f(attn + c4);
    float4 b1v = ld4f(bu2 + c4), b2v = ld4f(bd + c4);
    float4 bsum{b1v.x + b2v.x, b1v.y + b2v.y, b1v.z + b2v.z, b1v.w + b2v.w};
    float4 wd0 = ld4f(Wd + c4), wd1 = ld4f(Wd + DM + c4), wd2 = ld4f(Wd + 2 * DM + c4);
    float4 wd3 = ld4f(Wd + 3 * DM + c4), wd4 = ld4f(Wd + 4 * DM + c4), wd5 = ld4f(Wd + 5 * DM + c4);
    int q = gw;
    int qs = 0, q2 = 0, q1 = 0, qd = 0;
    F3 P0{0, 0, 0}, P1{0, 0, 0}, P2{0, 0, 0}, P3{0, 0, 0};
    if (q < NQ) {
      qs = qdx[q]; q2 = qdx[NQ + q]; q1 = qdx[2 * NQ + q]; qd = qdx[3 * NQ + q];
      P0 = ldp(pos, qs); P1 = ldp(pos, q2); P2 = ldp(pos, q1); P3 = ldp(pos, qd);
    }
    while (q < NQ) {
      int qn = q + nw;
      int nqs = 0, nq2 = 0, nq1 = 0, nqd = 0;
      F3 nP0{0, 0, 0}, nP1{0, 0, 0}, nP2{0, 0, 0}, nP3{0, 0, 0};
      if (qn < NQ) {
        nqs = qdx[qn]; nq2 = qdx[NQ + qn]; nq1 = qdx[2 * NQ + qn]; nqd = qdx[3 * NQ + qn];
        nP0 = ldp(pos, nqs); nP1 = ldp(pos, nq2); nP2 = ldp(pos, nq1); nP3 = ldp(pos, nqd);
      }
      float d3 = fminf(fmaxf(norm3(sub3(P0, P3)), 0.05f), 10.f);
      float a1f = angle_at(P0, P1, P2);
      float a2f = angle_at(P1, P2, P3);
      float dh = dihedral_f(P0, P1, P2, P3);
      float f0 = a1f, f1 = a1f * a1f, f2 = a2f, f3 = a2f * a2f, f4 = dh, f5 = dh * dh;
      float4 dm;
      dm.x = bsum.x + f0 * wd0.x + f1 * wd1.x + f2 * wd2.x + f3 * wd3.x + f4 * wd4.x + f5 * wd5.x;
      dm.y = bsum.y + f0 * wd0.y + f1 * wd1.y + f2 * wd2.y + f3 * wd3.y + f4 * wd4.y + f5 * wd5.y;
      dm.z = bsum.z + f0 * wd0.z + f1 * wd1.z + f2 * wd2.z + f3 * wd3.z + f4 * wd4.z + f5 * wd5.z;
      dm.w = bsum.w + f0 * wd0.w + f1 * wd1.w + f2 * wd2.w + f3 * wd3.w + f4 * wd4.w + f5 * wd5.w;
      dm = rbf_acc(d3, Wu2, dm, c4);
      float4 v0 = ld4bf(p_src + (size_t)qs * DM + c4);
      float4 v1 = ld4bf(p_mid2 + (size_t)q2 * DM + c4);
      float4 v2 = ld4bf(p_mid1 + (size_t)q1 * DM + c4);
      float4 v3 = ld4bf(p_dst + (size_t)qd * DM + c4);
      float s0 = lk((v0.x + v1.x + v2.x + v3.x) * dm.x);
      float s1 = lk((v0.y + v1.y + v2.y + v3.y) * dm.y);
      float s2 = lk((v0.z + v1.z + v2.z + v3.z) * dm.z);
      float s3 = lk((v0.w + v1.w + v2.w + v3.w) * dm.w);
      float part = av.x * s0 + av.y * s1 + av.z * s2 + av.w * s3;
      part += __shfl_xor(part, 1, 64);
      part += __shfl_xor(part, 2, 64);
      part += __shfl_xor(part, 4, 64);
      if ((lane & 7) == 0) score3[(size_t)q * 8 + (lane >> 3)] = part;
      rmax = fmaxf(rmax, part);
      q = qn; qs = nqs; q2 = nq2; q1 = nq1; qd = nqd;
      P0 = nP0; P1 = nP1; P2 = nP2; P3 = nP3;
    }
    for (int m = 32; m; m >>= 1) rmax = fmaxf(rmax, __shfl_xor(rmax, m, 64));
    if (lane == 0) atomicMax(gmax + 2, f2o(rmax));
  }
}

// ---- fused gather: 3*NN waves, writes bf16 out1/out2/out3 ----
__global__ __launch_bounds__(256) void gather_all(
    const u16* __restrict__ p_src, const u16* __restrict__ p_mid2,
    const u16* __restrict__ p_mid1,
    const int* __restrict__ eidx, const int* __restrict__ tdx, const int* __restrict__ qdx,
    const float* __restrict__ score1, const float* __restrict__ score2,
    const float* __restrict__ score3,
    const int* __restrict__ offall, const int* __restrict__ eidall,
    const u32* __restrict__ gmax,
    u16* __restrict__ out1, u16* __restrict__ out2, u16* __restrict__ out3) {
  const int W = (blockIdx.x * blockDim.x + threadIdx.x) >> 6;
  if (W >= 3 * NN) return;
  const int lane = threadIdx.x & 63;
  const int h = lane >> 3;
  const int c4 = lane * 4;
  const int hop = (W < NN) ? 0 : ((W < 2 * NN) ? 1 : 2);
  const int node = W - hop * NN;
  const int* offp = offall + (size_t)hop * (NN + 1);
  const int* eidp = eidall + ((hop == 0) ? 0 : ((hop == 1) ? NE : (NE + NT)));
  const int* gsrc = (hop == 0) ? eidx : ((hop == 1) ? tdx : qdx);
  const float* scr = (hop == 0) ? score1 : ((hop == 1) ? score2 : score3);
  const u16* sv = (hop == 0) ? p_mid1 : ((hop == 1) ? p_mid2 : p_src);
  u16* outp = (hop == 0) ? out1 : ((hop == 1) ? out2 : out3);
  const float g = o2f(gmax[hop]);
  const int s0 = offp[node], s1 = offp[node + 1];
  float4 vacc{0.f, 0.f, 0.f, 0.f};
  float wsum = 0.f;
  for (int j = s0; j < s1; ++j) {
    int e = eidp[j];
    int s = gsrc[e];
    float ev = expf(scr[(size_t)e * 8 + h] - g);
    wsum += ev;
    float4 v = ld4bf(sv + (size_t)s * DM + c4);
    vacc.x = fmaf(ev, v.x, vacc.x);
    vacc.y = fmaf(ev, v.y, vacc.y);
    vacc.z = fmaf(ev, v.z, vacc.z);
    vacc.w = fmaf(ev, v.w, vacc.w);
  }
  float inv = 1.f / (wsum + 1e-16f);
  ushort4 o;
  o.x = f2bf(vacc.x * inv);
  o.y = f2bf(vacc.y * inv);
  o.z = f2bf(vacc.z * inv);
  o.w = f2bf(vacc.w * inv);
  *reinterpret_cast<ushort4*>(outp + (size_t)node * DM + c4) = o;
}

// ---- fused output GEMM (K=896) + LayerNorm + PReLU, single write of d_out ----
__global__ __launch_bounds__(256) void gemm_ln(
    const u16* __restrict__ out1, const u16* __restrict__ out2,
    const u16* __restrict__ out3, const void* __restrict__ x,
    const int* __restrict__ flags, const float* __restrict__ fp,
    float* __restrict__ outp) {
  __shared__ float smA[16 * 768];  // 48 KB: out1|out2|out3 per row
  __shared__ float smX[16 * FIN];  // 8 KB
  __shared__ float redS[4][16], redQ[4][16];
  const int c = threadIdx.x;
  const int n0 = blockIdx.x * 16;
  const int isf = flags[1];
  const float* W1 = fp + 165888;
  const float* W2 = fp + 231680;
  const float* W3 = fp + 297472;
  const float* Wr = fp + 364032;
  const float* b1 = fp + 231424;
  const float* b2 = fp + 297216;
  const float* b3 = fp + 363008;
  const float* bias = fp + 396800;
  const float* ln_g = fp + 397056;
  const float* ln_b = fp + 397312;
  const float* prelu = fp + 397568;

  for (int i = c; i < 16 * 256; i += 256) {
    int r = i >> 8, k = i & 255;
    size_t gi = (size_t)(n0 + r) * DM + k;
    smA[r * 768 + k] = bf2f(out1[gi]);
    smA[r * 768 + 256 + k] = bf2f(out2[gi]);
    smA[r * 768 + 512 + k] = bf2f(out3[gi]);
  }
  for (int i = c; i < 16 * FIN; i += 256) {
    int r = i >> 7, k = i & 127;
    smX[r * FIN + k] = ldsc(x, isf, (size_t)(n0 + r) * FIN + k);
  }
  __syncthreads();

  float acc[16];
  float base = b1[c] + b2[c] + b3[c] + bias[c];
#pragma unroll
  for (int r = 0; r < 16; ++r) acc[r] = base;

  const float* Ws[3] = {W1, W2, W3};
#pragma unroll 1
  for (int seg = 0; seg < 3; ++seg) {
    const float* W = Ws[seg];
    const float* A = smA + seg * 256;
    for (int k = 0; k < 256; k += 4) {
      float w0 = W[k * DM + c], w1 = W[(k + 1) * DM + c];
      float w2 = W[(k + 2) * DM + c], w3 = W[(k + 3) * DM + c];
#pragma unroll
      for (int r = 0; r < 16; ++r) {
        float4 a = *reinterpret_cast<const float4*>(&A[r * 768 + k]);
        acc[r] = fmaf(a.x, w0, acc[r]);
        acc[r] = fmaf(a.y, w1, acc[r]);
        acc[r] = fmaf(a.z, w2, acc[r]);
        acc[r] = fmaf(a.w, w3, acc[r]);
      }
    }
  }
  for (int k = 0; k < FIN; k += 4) {
    float w0 = Wr[k * DM + c], w1 = Wr[(k + 1) * DM + c];
    float w2 = Wr[(k + 2) * DM + c], w3 = Wr[(k + 3) * DM + c];
#pragma unroll
    for (int r = 0; r < 16; ++r) {
      float4 a = *reinterpret_cast<const float4*>(&smX[r * FIN + k]);
      acc[r] = fmaf(a.x, w0, acc[r]);
      acc[r] = fmaf(a.y, w1, acc[r]);
      acc[r] = fmaf(a.z, w2, acc[r]);
      acc[r] = fmaf(a.w, w3, acc[r]);
    }
  }

  // LayerNorm reduction across the 256 threads (= 256 channels) per row
  const int w = c >> 6, l = c & 63;
#pragma unroll
  for (int r = 0; r < 16; ++r) {
    float s = acc[r], q = acc[r] * acc[r];
    for (int m = 32; m; m >>= 1) {
      s += __shfl_xor(s, m, 64);
      q += __shfl_xor(q, m, 64);
    }
    if (l == 0) { redS[w][r] = s; redQ[w][r] = q; }
  }
  __syncthreads();
  float g = ln_g[c], bt = ln_b[c], pw = prelu[0];
#pragma unroll
  for (int r = 0; r < 16; ++r) {
    float S = redS[0][r] + redS[1][r] + redS[2][r] + redS[3][r];
    float Q = redQ[0][r] + redQ[1][r] + redQ[2][r] + redQ[3][r];
    float mu = S * (1.f / 256.f);
    float var = fmaxf(Q * (1.f / 256.f) - mu * mu, 0.f);
    float y = (acc[r] - mu) * rsqrtf(var + 1e-5f) * g + bt;
    outp[(size_t)(n0 + r) * DM + c] = (y >= 0.f) ? y : pw * y;
  }
}

extern "C" void kernel_launch(void* const* d_in, const int* in_sizes, int n_in,
                              void* d_out, int out_size, void* d_ws, size_t ws_size,
                              hipStream_t stream) {
  const void* x = d_in[0];
  const void* pos = d_in[1];
  const int* eidx = (const int*)d_in[2];
  const int* tdx = (const int*)d_in[3];
  const int* qdx = (const int*)d_in[4];
  const void* eattr = d_in[5];
  float* outp = (float*)d_out;

  // workspace layout (~216 MB; proven safe <= ~221 MB)
  u16* p_src = (u16*)d_ws;
  u16* p_mid2 = p_src + (size_t)NN * DM;
  u16* p_mid1 = p_mid2 + (size_t)NN * DM;
  u16* p_dst = p_mid1 + (size_t)NN * DM;
  u16* out1 = p_dst + (size_t)NN * DM;
  u16* out2 = out1 + (size_t)NN * DM;
  u16* out3 = out2 + (size_t)NN * DM;
  float* score1 = (float*)(out3 + (size_t)NN * DM);   // NE*8
  float* score2 = score1 + (size_t)NE * 8;            // NT*8
  float* score3 = score2 + (size_t)NT * 8;            // NQ*8
  float* posf = score3 + (size_t)NQ * 8;              // NN*3
  float* fp = posf + (size_t)NN * 3;                  // staged params
  int* deg = (int*)(fp + TOTALP + 3);                 // 3*NN
  int* off = deg + 3 * NN;                            // 3*(NN+1)
  int* cur = off + 3 * (NN + 1);                      // 3*NN
  int* eid = cur + 3 * NN;                            // NE+NT+NQ
  u32* gmax = (u32*)(eid + NE + NT + NQ);
  int* flags = (int*)(gmax + 4);

  const float* W_src = fp + 0;
  const float* W_dst = fp + 32768;
  const float* W_mid1 = fp + 65536;
  const float* W_mid2 = fp + 98304;

  init_detect<<<1, 256, 0, stream>>>((const u32*)eattr, (const u32*)d_in[33], gmax, flags);

  PtrTab tab;
  for (int i = 0; i < 30; ++i) tab.p[i] = d_in[6 + i];
  convert_params<<<512, 256, 0, stream>>>(tab, flags, fp);
  convert_pos<<<587, 256, 0, stream>>>(pos, flags, posf);

  proj4_kernel<<<NN / 16, 256, 0, stream>>>(x, flags, W_src, W_mid2, W_mid1, W_dst,
                                            p_src, p_mid2, p_mid1, p_dst);

  // CSR for all 3 hops
  hipMemsetAsync(deg, 0, (size_t)3 * NN * 4, stream);
  hist_all<<<1024, 256, 0, stream>>>(eidx + NE, tdx + 2 * NT, qdx + 3 * NQ, deg);
  scan_all<<<3, 1024, 0, stream>>>(deg, off, cur);
  fill_all<<<1024, 256, 0, stream>>>(eidx + NE, tdx + 2 * NT, qdx + 3 * NQ, cur, eid);

  // fused score pass
  pass1_all<<<4608, 256, 0, stream>>>(posf, eidx, tdx, qdx, eattr, flags,
                                      p_src, p_mid2, p_mid1, p_dst, fp,
                                      score1, score2, score3, gmax);

  // fused softmax-aggregate
  gather_all<<<(3 * NN + 3) / 4, 256, 0, stream>>>(p_src, p_mid2, p_mid1,
                                                   eidx, tdx, qdx,
                                                   score1, score2, score3,
                                                   off, eid, gmax, out1, out2, out3);

  // fused output GEMM + LN + PReLU
  gemm_ln<<<NN / 16, 256, 0, stream>>>(out1, out2, out3, x, flags, fp, outp);
}